// Round 7
// baseline (895.355 us; speedup 1.0000x reference)
//
#include <hip/hip_runtime.h>

#define NN 50000
#define NE 800000
#define NG 128
#define HD 128
#define NL 4
#define BN_EPS 1e-5f
#define REP 32
#define WP 136
#define NB 392
#define EPB 4096

typedef __attribute__((ext_vector_type(8))) short bf16x8;
typedef __attribute__((ext_vector_type(4))) float f32x4;

__device__ __forceinline__ unsigned short f2bf(float f) {
    unsigned u = __float_as_uint(f);
    u += 0x7FFFu + ((u >> 16) & 1u);  // RNE
    return (unsigned short)(u >> 16);
}
__device__ __forceinline__ float bfval(unsigned short h) { return __uint_as_float((unsigned)h << 16); }
__device__ __forceinline__ float bflo(unsigned u) { return __uint_as_float(u << 16); }
__device__ __forceinline__ float bfhi(unsigned u) { return __uint_as_float(u & 0xFFFF0000u); }

__device__ __forceinline__ void split2(float a, float b, unsigned& hi, unsigned& lo) {
    unsigned ua = __float_as_uint(a), ub = __float_as_uint(b);
    hi = (ua >> 16) | (ub & 0xFFFF0000u);
    float ra = a - __uint_as_float(ua & 0xFFFF0000u);
    float rb = b - __uint_as_float(ub & 0xFFFF0000u);
    lo = (unsigned)f2bf(ra) | ((unsigned)f2bf(rb) << 16);
}
__device__ __forceinline__ unsigned pack2(float a, float b) {
    return (unsigned)f2bf(a) | ((unsigned)f2bf(b) << 16);
}

__device__ __forceinline__ void bn_pre(const float* SQbase,
                                       const float* gam, const float* bet,
                                       float inv_cnt, int t, float* scs, float* shs) {
    if (gam == nullptr) { scs[t] = 1.f; shs[t] = 0.f; return; }
    float s = 0.f, q = 0.f;
#pragma unroll
    for (int r = 0; r < REP; r++) {
        s += SQbase[r * 256 + t];
        q += SQbase[r * 256 + 128 + t];
    }
    float m = s * inv_cnt;
    float var = fmaxf(fmaf(q, inv_cnt, -m * m), 0.f);
    float inv = rsqrtf(var + BN_EPS);
    float sc = gam[t] * inv;
    scs[t] = sc;
    shs[t] = fmaf(-m, sc, bet[t]);
}

// -------- fused setup: embed (3125) | cvtw 14 segs incl. head W (896) | hist (3125) -----
__global__ __launch_bounds__(256) void setup_kernel(const int* __restrict__ ids,
                                                    const float* __restrict__ emb,
                                                    unsigned short* __restrict__ Yb,
                                                    const float* __restrict__ iw1,
                                                    const float* __restrict__ iw2,
                                                    const float* __restrict__ mw1,
                                                    const float* __restrict__ mw2,
                                                    const float* __restrict__ hw1,
                                                    const float* __restrict__ hw2,
                                                    const float* __restrict__ hw3,
                                                    const float* __restrict__ hw4,
                                                    unsigned short* __restrict__ Wh,
                                                    unsigned short* __restrict__ Wl,
                                                    const int* __restrict__ dst,
                                                    int* __restrict__ deg) {
    int b = blockIdx.x, t = threadIdx.x;
    if (b < 3125) {
        int i = b * 256 + t;
        if (i < NN * 16) {
            int node = i >> 4, g = i & 15;
            int id = ids[node];
            const float* p = emb + (size_t)id * HD + 8 * g;
            float4 a = *(const float4*)p;
            float4 bb = *(const float4*)(p + 4);
            uint4 o;
            o.x = pack2(a.x, a.y); o.y = pack2(a.z, a.w);
            o.z = pack2(bb.x, bb.y); o.w = pack2(bb.z, bb.w);
            *(uint4*)(Yb + (size_t)node * HD + 8 * g) = o;
        }
    } else if (b < 4021) {
        int i = (b - 3125) * 256 + t;
        if (i < 229376) {
            int seg = i >> 14, loc = i & 16383;
            float v;
            if (seg == 0)       v = iw1[loc];
            else if (seg == 1)  v = iw2[loc];
            else if (seg < 6)   v = mw1[(seg - 2) * 16384 + loc];
            else if (seg < 10)  v = mw2[(seg - 6) * 16384 + loc];
            else if (seg == 10) v = hw1[loc];
            else if (seg == 11) v = hw2[loc];
            else if (seg == 12) v = hw3[loc];
            else                v = hw4[loc];
            int k = loc >> 7, n = loc & 127;
            unsigned short h = f2bf(v);
            float r = v - bfval(h);
            Wh[seg * 16384 + n * 128 + k] = h;
            Wl[seg * 16384 + n * 128 + k] = f2bf(r);
        }
    } else {
        int e = (b - 4021) * 256 + t;
        if (e < NE) atomicAdd(&deg[dst[e]], 1);
    }
}

// ---------------- ybn: 64 rows/block (bn_pre amortized 4x) ----------------
__global__ __launch_bounds__(256) void ybn_kernel(const float* __restrict__ X,
                                                  const float* __restrict__ SQin,
                                                  const float* __restrict__ gam,
                                                  const float* __restrict__ bet,
                                                  unsigned short* __restrict__ Yb) {
    __shared__ float scs[HD], shs[HD];
    int t = threadIdx.x;
    if (t < HD) bn_pre(SQin, gam, bet, 1.f / NN, t, scs, shs);
    __syncthreads();
    int c8 = (t & 15) * 8;
    float4 s0 = *(const float4*)&scs[c8], s1 = *(const float4*)&scs[c8 + 4];
    float4 h0 = *(const float4*)&shs[c8], h1 = *(const float4*)&shs[c8 + 4];
#pragma unroll
    for (int ch = 0; ch < 4; ch++) {
        int row = blockIdx.x * 64 + ch * 16 + (t >> 4);
        if (row < NN) {
            const float* p = X + (size_t)row * HD + c8;
            float4 v0 = *(const float4*)p;
            float4 v1 = *(const float4*)(p + 4);
            float f0 = fmaxf(fmaf(v0.x, s0.x, h0.x), 0.f), f1 = fmaxf(fmaf(v0.y, s0.y, h0.y), 0.f);
            float f2 = fmaxf(fmaf(v0.z, s0.z, h0.z), 0.f), f3 = fmaxf(fmaf(v0.w, s0.w, h0.w), 0.f);
            float f4 = fmaxf(fmaf(v1.x, s1.x, h1.x), 0.f), f5 = fmaxf(fmaf(v1.y, s1.y, h1.y), 0.f);
            float f6 = fmaxf(fmaf(v1.z, s1.z, h1.z), 0.f), f7 = fmaxf(fmaf(v1.w, s1.w, h1.w), 0.f);
            uint4 o;
            o.x = pack2(f0, f1); o.y = pack2(f2, f3);
            o.z = pack2(f4, f5); o.w = pack2(f6, f7);
            *(uint4*)(Yb + (size_t)row * HD + c8) = o;
        }
    }
}

// ---------------- CSR scans (scan2 folded into scan3) ----------------
__global__ __launch_bounds__(1024) void scan1_kernel(const int* __restrict__ deg,
                                                     int* __restrict__ rowptr,
                                                     int* __restrict__ blockSum) {
    __shared__ int s[1024];
    int b = blockIdx.x, t = threadIdx.x;
    int i = b * 1024 + t;
    int v = (i < NN) ? deg[i] : 0;
    s[t] = v;
    __syncthreads();
    for (int off = 1; off < 1024; off <<= 1) {
        int u = (t >= off) ? s[t - off] : 0;
        __syncthreads();
        s[t] += u;
        __syncthreads();
    }
    if (i < NN) rowptr[i] = s[t] - v;
    if (t == 1023) blockSum[b] = s[1023];
}

__global__ __launch_bounds__(1024) void scan3_kernel(int* __restrict__ rowptr,
                                                     int* __restrict__ cursor,
                                                     const int* __restrict__ blockSum,
                                                     int* __restrict__ bucketCursor,
                                                     int nblocks) {
    __shared__ int sOff, sTot;
    int b = blockIdx.x, t = threadIdx.x;
    if (t < 64) {
        int orig = (t < nblocks) ? blockSum[t] : 0;
        int v = orig;
        for (int off = 1; off < 64; off <<= 1) {
            int u = __shfl_up(v, off, 64);
            if (t >= off) v += u;
        }
        if (t == b) sOff = v - orig;
        if (t == nblocks - 1) sTot = v;
    }
    __syncthreads();
    int i = b * 1024 + t;
    if (i < NN) {
        int r = rowptr[i] + sOff;
        rowptr[i] = r;
        cursor[i] = r;
        if ((i & 127) == 0) bucketCursor[i >> 7] = r;
    }
    if (b == nblocks - 1 && t == 0) rowptr[NN] = sTot;
}

// ---------------- bin ----------------
__global__ __launch_bounds__(256) void bin_kernel(const int* __restrict__ src,
                                                  const int* __restrict__ dst,
                                                  const int* __restrict__ attr,
                                                  int* __restrict__ bucketCursor,
                                                  uint2* __restrict__ ebuf) {
    __shared__ int cnt[512];
    __shared__ int sc[512], sc2[512];
    __shared__ int base[512];
    __shared__ int garr[NB];
    __shared__ int wof[NB];
    __shared__ uint2 stage[EPB];
    int t = threadIdx.x;
    int e0 = blockIdx.x * EPB;
    for (int i = t; i < 512; i += 256) cnt[i] = 0;
    __syncthreads();
    int myb[16]; unsigned myv[16]; int myd[16];
#pragma unroll
    for (int j = 0; j < 16; j++) {
        int e = e0 + t + j * 256;
        if (e < NE) {
            int d = dst[e];
            myd[j] = d;
            myv[j] = (unsigned)src[e] | ((unsigned)attr[e] << 16);
            myb[j] = d >> 7;
            atomicAdd(&cnt[myb[j]], 1);
        } else myb[j] = -1;
    }
    __syncthreads();
    for (int k = t; k < 512; k += 256) sc[k] = cnt[k];
    __syncthreads();
    int* sp = sc; int* dp = sc2;
    for (int off = 1; off < 512; off <<= 1) {
        for (int k = t; k < 512; k += 256) dp[k] = sp[k] + (k >= off ? sp[k - off] : 0);
        __syncthreads();
        int* tmp = sp; sp = dp; dp = tmp;
    }
    for (int k = t; k < 512; k += 256) base[k] = sp[k] - cnt[k];
    int total = sp[511];
    __syncthreads();
    for (int b = t; b < NB; b += 256) {
        wof[b] = 0;
        if (cnt[b] > 0) garr[b] = atomicAdd(&bucketCursor[b], cnt[b]);
    }
    __syncthreads();
#pragma unroll
    for (int j = 0; j < 16; j++) {
        if (myb[j] >= 0) {
            int slot = base[myb[j]] + atomicAdd(&wof[myb[j]], 1);
            stage[slot] = make_uint2(myv[j], (unsigned)myd[j]);
        }
    }
    __syncthreads();
    for (int i = t; i < total; i += 256) {
        uint2 u = stage[i];
        int b = (int)(u.y >> 7);
        ebuf[garr[b] + (i - base[b])] = u;
    }
}

// ---------------- place ----------------
__global__ __launch_bounds__(256) void place_kernel(const uint2* __restrict__ ebuf,
                                                    const int* __restrict__ rowptr,
                                                    int* __restrict__ cursor,
                                                    unsigned* __restrict__ csr) {
    int b = blockIdx.x;
    int n0 = b * 128;
    int n1 = n0 + 128; if (n1 > NN) n1 = NN;
    int es = rowptr[n0], ee = rowptr[n1];
    for (int i = es + threadIdx.x; i < ee; i += 256) {
        uint2 u = ebuf[i];
        int pos = atomicAdd(&cursor[u.y], 1);
        csr[pos] = u.x;
    }
}

// ---------------- GINE conv ----------------
__device__ __forceinline__ void gine_acc(const unsigned short* __restrict__ Yb,
                                         const float* __restrict__ elds,
                                         unsigned p, int cq, float mask, float* a) {
    uint4 q = *(const uint4*)(Yb + (size_t)(p & 0xFFFFu) * HD + 8 * cq);
    const float* ep = elds + (p >> 16) * HD + 8 * cq;
    float4 e0 = *(const float4*)ep;
    float4 e1 = *(const float4*)(ep + 4);
    a[0] += mask * fmaxf(bflo(q.x) + e0.x, 0.f);
    a[1] += mask * fmaxf(bfhi(q.x) + e0.y, 0.f);
    a[2] += mask * fmaxf(bflo(q.y) + e0.z, 0.f);
    a[3] += mask * fmaxf(bfhi(q.y) + e0.w, 0.f);
    a[4] += mask * fmaxf(bflo(q.z) + e1.x, 0.f);
    a[5] += mask * fmaxf(bfhi(q.z) + e1.y, 0.f);
    a[6] += mask * fmaxf(bflo(q.w) + e1.z, 0.f);
    a[7] += mask * fmaxf(bfhi(q.w) + e1.w, 0.f);
}

__global__ __launch_bounds__(256) void conv_kernel(const unsigned short* __restrict__ Yb,
                                                   const int* __restrict__ rowptr,
                                                   const unsigned* __restrict__ csr,
                                                   const float* __restrict__ edge_emb,
                                                   const float* __restrict__ eps, int layer,
                                                   unsigned short* __restrict__ Ah,
                                                   unsigned short* __restrict__ Al) {
    __shared__ float elds[8 * HD];
    int t = threadIdx.x;
    ((float4*)elds)[t] = ((const float4*)edge_emb)[t];
    __syncthreads();
    int wave = t >> 6, lane = t & 63;
    int node = blockIdx.x * 4 + wave;
    if (node >= NN) return;
    int sub = lane >> 4, cq = lane & 15;
    int lo = rowptr[node], hi = rowptr[node + 1];
    float a[8];
#pragma unroll
    for (int i = 0; i < 8; i++) a[i] = 0.f;
    for (int base = lo; base < hi; base += 64) {
        unsigned pl = 0;
        int cnt = hi - base; if (cnt > 64) cnt = 64;
        if (base + lane < hi) pl = csr[base + lane];
        int j = 0;
        for (; j + 16 <= cnt; j += 16) {
            unsigned pa = __shfl(pl, j + sub, 64);
            unsigned pb = __shfl(pl, j + 4 + sub, 64);
            unsigned pc = __shfl(pl, j + 8 + sub, 64);
            unsigned pd = __shfl(pl, j + 12 + sub, 64);
            gine_acc(Yb, elds, pa, cq, 1.f, a);
            gine_acc(Yb, elds, pb, cq, 1.f, a);
            gine_acc(Yb, elds, pc, cq, 1.f, a);
            gine_acc(Yb, elds, pd, cq, 1.f, a);
        }
        for (; j + 8 <= cnt; j += 8) {
            unsigned pa = __shfl(pl, j + sub, 64);
            unsigned pb = __shfl(pl, j + 4 + sub, 64);
            gine_acc(Yb, elds, pa, cq, 1.f, a);
            gine_acc(Yb, elds, pb, cq, 1.f, a);
        }
        for (; j < cnt; j += 4) {
            int je = j + sub;
            bool val = (je < cnt);
            unsigned p = __shfl(pl, val ? je : j, 64);
            gine_acc(Yb, elds, p, cq, val ? 1.f : 0.f, a);
        }
    }
#pragma unroll
    for (int i = 0; i < 8; i++) {
        a[i] += __shfl_xor(a[i], 16, 64);
        a[i] += __shfl_xor(a[i], 32, 64);
    }
    if (sub == 0) {
        float g = 1.f + eps[layer];
        uint4 q = *(const uint4*)(Yb + (size_t)node * HD + 8 * cq);
        float o0 = fmaf(g, bflo(q.x), a[0]), o1 = fmaf(g, bfhi(q.x), a[1]);
        float o2 = fmaf(g, bflo(q.y), a[2]), o3 = fmaf(g, bfhi(q.y), a[3]);
        float o4 = fmaf(g, bflo(q.z), a[4]), o5 = fmaf(g, bfhi(q.z), a[5]);
        float o6 = fmaf(g, bflo(q.w), a[6]), o7 = fmaf(g, bfhi(q.w), a[7]);
        uint4 H, L;
        split2(o0, o1, H.x, L.x);
        split2(o2, o3, H.y, L.y);
        split2(o4, o5, H.z, L.z);
        split2(o6, o7, H.w, L.w);
        *(uint4*)(Ah + (size_t)node * HD + 8 * cq) = H;
        *(uint4*)(Al + (size_t)node * HD + 8 * cq) = L;
    }
}

// ------- fused MFMA layer: GEMM1 -> device barrier (stats) -> GEMM2+BN-act --------------
// 391 blocks x 512 thr; LDS ~70KB -> 2 blocks/CU -> all 391 co-resident (spin is safe).
// Barrier poll is a NON-RMW agent-scope load (R6's atomicAdd(p,0) spin saturated the
// L2 atomic unit and starved the arrival increments).
__global__ __launch_bounds__(512, 4) void mm_fused(const unsigned short* __restrict__ Ah,
                                                   const unsigned short* __restrict__ Al,
                                                   const unsigned short* __restrict__ Wh1,
                                                   const unsigned short* __restrict__ Wl1,
                                                   const float* __restrict__ bias1,
                                                   const unsigned short* __restrict__ Wh2,
                                                   const unsigned short* __restrict__ Wl2,
                                                   const float* __restrict__ bias2,
                                                   const float* __restrict__ gam,
                                                   const float* __restrict__ bet,
                                                   float* __restrict__ Bbuf,
                                                   float* __restrict__ S1,
                                                   float* __restrict__ X,
                                                   float* __restrict__ S2,
                                                   int* __restrict__ barCnt, int nblk) {
    __shared__ unsigned short WhS[128 * WP];
    __shared__ unsigned short WlS[128 * WP];
    __shared__ float scs[HD], shs[HD];
    int t = threadIdx.x;
    int rowblk = blockIdx.x;
#pragma unroll
    for (int i = 0; i < 4; i++) {
        int idx = t + i * 512;
        int col = idx >> 4, kk = (idx & 15) * 8;
        *(uint4*)(WhS + col * WP + kk) = *(const uint4*)(Wh1 + (size_t)col * HD + kk);
        *(uint4*)(WlS + col * WP + kk) = *(const uint4*)(Wl1 + (size_t)col * HD + kk);
    }
    __syncthreads();
    int w = t >> 6, lane = t & 63;
    int quad = lane >> 4, nl = lane & 15;
    int row0 = rowblk * 128 + w * 16;
    int rA0 = row0 + nl;
    bool ok0 = rA0 < NN;
    bool fullblk = (rowblk * 128 + 128 <= NN);
    int rep = (rowblk & (REP - 1)) * 256;
    int baserow = row0 + quad * 4;
    {   // ---- phase 1: Bbuf = Ah|Al @ W1 (+b1), stats -> S1 ----
        f32x4 acc[8];
#pragma unroll
        for (int i = 0; i < 8; i++) acc[i] = (f32x4){0.f, 0.f, 0.f, 0.f};
#pragma unroll
        for (int kc = 0; kc < 4; kc++) {
            int k0 = kc * 32 + quad * 8;
            bf16x8 a0h = ok0 ? *(const bf16x8*)(Ah + (size_t)rA0 * HD + k0) : (bf16x8)0;
            bf16x8 a0l = ok0 ? *(const bf16x8*)(Al + (size_t)rA0 * HD + k0) : (bf16x8)0;
#pragma unroll
            for (int c = 0; c < 8; c++) {
                int wof = (c * 16 + nl) * WP + k0;
                bf16x8 bh = *(const bf16x8*)(WhS + wof);
                bf16x8 bl = *(const bf16x8*)(WlS + wof);
                acc[c] = __builtin_amdgcn_mfma_f32_16x16x32_bf16(a0h, bh, acc[c], 0, 0, 0);
                acc[c] = __builtin_amdgcn_mfma_f32_16x16x32_bf16(a0l, bh, acc[c], 0, 0, 0);
                acc[c] = __builtin_amdgcn_mfma_f32_16x16x32_bf16(a0h, bl, acc[c], 0, 0, 0);
            }
        }
        if (fullblk) {
#pragma unroll
            for (int c = 0; c < 8; c++) {
                int col = c * 16 + nl;
                float bv = bias1 ? bias1[col] : 0.f;
                f32x4 v = acc[c];
                float s = 0.f, qq = 0.f;
#pragma unroll
                for (int r = 0; r < 4; r++) {
                    float val = v[r] + bv;
                    Bbuf[(size_t)(baserow + r) * HD + col] = val;
                    s += val;
                    qq += val * val;
                }
                s += __shfl_xor(s, 16, 64);  s += __shfl_xor(s, 32, 64);
                qq += __shfl_xor(qq, 16, 64); qq += __shfl_xor(qq, 32, 64);
                if (quad == 0) {
                    atomicAdd(&S1[rep + col], s);
                    atomicAdd(&S1[rep + 128 + col], qq);
                }
            }
        } else {
#pragma unroll
            for (int c = 0; c < 8; c++) {
                int col = c * 16 + nl;
                float bv = bias1 ? bias1[col] : 0.f;
                f32x4 v = acc[c];
                float s = 0.f, qq = 0.f;
#pragma unroll
                for (int r = 0; r < 4; r++) {
                    int grow = baserow + r;
                    float val = v[r] + bv;
                    if (grow < NN) {
                        Bbuf[(size_t)grow * HD + col] = val;
                        s += val;
                        qq += val * val;
                    }
                }
                s += __shfl_xor(s, 16, 64);  s += __shfl_xor(s, 32, 64);
                qq += __shfl_xor(qq, 16, 64); qq += __shfl_xor(qq, 32, 64);
                if (quad == 0) {
                    atomicAdd(&S1[rep + col], s);
                    atomicAdd(&S1[rep + 128 + col], qq);
                }
            }
        }
    }
    // ---- device barrier: all blocks' S1 atomics done ----
    __syncthreads();
    if (t == 0) {
        __threadfence();
        atomicAdd(barCnt, 1);
        while (__hip_atomic_load(barCnt, __ATOMIC_RELAXED, __HIP_MEMORY_SCOPE_AGENT) < nblk)
            __builtin_amdgcn_s_sleep(8);
        __threadfence();
    }
    __syncthreads();
    // ---- stage W2 over W1; bn_pre from S1 ----
    if (t < HD) bn_pre(S1, gam, bet, 1.f / NN, t, scs, shs);
#pragma unroll
    for (int i = 0; i < 4; i++) {
        int idx = t + i * 512;
        int col = idx >> 4, kk = (idx & 15) * 8;
        *(uint4*)(WhS + col * WP + kk) = *(const uint4*)(Wh2 + (size_t)col * HD + kk);
        *(uint4*)(WlS + col * WP + kk) = *(const uint4*)(Wl2 + (size_t)col * HD + kk);
    }
    __syncthreads();
    {   // ---- phase 2: X = relu(BN(Bbuf)) @ W2 (+b2), stats -> S2 (Bbuf rows L2-local) ----
        f32x4 acc[8];
#pragma unroll
        for (int i = 0; i < 8; i++) acc[i] = (f32x4){0.f, 0.f, 0.f, 0.f};
#pragma unroll
        for (int kc = 0; kc < 4; kc++) {
            int k0 = kc * 32 + quad * 8;
            float4 s0 = *(const float4*)&scs[k0], s1 = *(const float4*)&scs[k0 + 4];
            float4 t0 = *(const float4*)&shs[k0], t1 = *(const float4*)&shs[k0 + 4];
            bf16x8 a0h, a0l;
            {
                float4 v0 = ok0 ? *(const float4*)(Bbuf + (size_t)rA0 * HD + k0) : make_float4(0, 0, 0, 0);
                float4 v1 = ok0 ? *(const float4*)(Bbuf + (size_t)rA0 * HD + k0 + 4) : make_float4(0, 0, 0, 0);
                float f0 = fmaxf(fmaf(v0.x, s0.x, t0.x), 0.f), f1 = fmaxf(fmaf(v0.y, s0.y, t0.y), 0.f);
                float f2 = fmaxf(fmaf(v0.z, s0.z, t0.z), 0.f), f3 = fmaxf(fmaf(v0.w, s0.w, t0.w), 0.f);
                float f4 = fmaxf(fmaf(v1.x, s1.x, t1.x), 0.f), f5 = fmaxf(fmaf(v1.y, s1.y, t1.y), 0.f);
                float f6 = fmaxf(fmaf(v1.z, s1.z, t1.z), 0.f), f7 = fmaxf(fmaf(v1.w, s1.w, t1.w), 0.f);
                if (!ok0) { f0 = f1 = f2 = f3 = f4 = f5 = f6 = f7 = 0.f; }
                unsigned h0, h1, h2, h3, l0, l1, l2, l3;
                split2(f0, f1, h0, l0); split2(f2, f3, h1, l1);
                split2(f4, f5, h2, l2); split2(f6, f7, h3, l3);
                a0h = __builtin_bit_cast(bf16x8, make_uint4(h0, h1, h2, h3));
                a0l = __builtin_bit_cast(bf16x8, make_uint4(l0, l1, l2, l3));
            }
#pragma unroll
            for (int c = 0; c < 8; c++) {
                int wof = (c * 16 + nl) * WP + k0;
                bf16x8 bh = *(const bf16x8*)(WhS + wof);
                bf16x8 bl = *(const bf16x8*)(WlS + wof);
                acc[c] = __builtin_amdgcn_mfma_f32_16x16x32_bf16(a0h, bh, acc[c], 0, 0, 0);
                acc[c] = __builtin_amdgcn_mfma_f32_16x16x32_bf16(a0l, bh, acc[c], 0, 0, 0);
                acc[c] = __builtin_amdgcn_mfma_f32_16x16x32_bf16(a0h, bl, acc[c], 0, 0, 0);
            }
        }
        if (fullblk) {
#pragma unroll
            for (int c = 0; c < 8; c++) {
                int col = c * 16 + nl;
                float bv = bias2 ? bias2[col] : 0.f;
                f32x4 v = acc[c];
                float s = 0.f, qq = 0.f;
#pragma unroll
                for (int r = 0; r < 4; r++) {
                    float val = v[r] + bv;
                    X[(size_t)(baserow + r) * HD + col] = val;
                    s += val;
                    qq += val * val;
                }
                s += __shfl_xor(s, 16, 64);  s += __shfl_xor(s, 32, 64);
                qq += __shfl_xor(qq, 16, 64); qq += __shfl_xor(qq, 32, 64);
                if (quad == 0) {
                    atomicAdd(&S2[rep + col], s);
                    atomicAdd(&S2[rep + 128 + col], qq);
                }
            }
        } else {
#pragma unroll
            for (int c = 0; c < 8; c++) {
                int col = c * 16 + nl;
                float bv = bias2 ? bias2[col] : 0.f;
                f32x4 v = acc[c];
                float s = 0.f, qq = 0.f;
#pragma unroll
                for (int r = 0; r < 4; r++) {
                    int grow = baserow + r;
                    float val = v[r] + bv;
                    if (grow < NN) {
                        X[(size_t)grow * HD + col] = val;
                        s += val;
                        qq += val * val;
                    }
                }
                s += __shfl_xor(s, 16, 64);  s += __shfl_xor(s, 32, 64);
                qq += __shfl_xor(qq, 16, 64); qq += __shfl_xor(qq, 32, 64);
                if (quad == 0) {
                    atomicAdd(&S2[rep + col], s);
                    atomicAdd(&S2[rep + 128 + col], qq);
                }
            }
        }
    }
}

// ---------------- readout ----------------
__global__ __launch_bounds__(256) void readout_kernel(const float* __restrict__ x,
                                                      const int* __restrict__ batch,
                                                      const float* __restrict__ SQin,
                                                      const float* __restrict__ gam,
                                                      const float* __restrict__ bet,
                                                      float* __restrict__ gout) {
    __shared__ int bat[256];
    __shared__ float scs[HD], shs[HD];
    int t = threadIdx.x;
    int rq = t >> 5, cq = t & 31;
    int r0 = blockIdx.x * 256;
    int i = r0 + t;
    bat[t] = (i < NN) ? batch[i] : -1;
    if (t < HD) bn_pre(SQin, gam, bet, 1.f / NN, t, scs, shs);
    __syncthreads();
    float4 s4 = *(const float4*)&scs[4 * cq];
    float4 h4 = *(const float4*)&shs[4 * cq];
    float4 acc = make_float4(0.f, 0.f, 0.f, 0.f);
    int gcur = -1;
    for (int j = rq; j < 256; j += 8) {
        int r = r0 + j;
        if (r >= NN) break;
        int g = bat[j];
        if (g != gcur) {
            if (gcur >= 0) {
                atomicAdd(&gout[(size_t)gcur * HD + 4 * cq + 0], acc.x);
                atomicAdd(&gout[(size_t)gcur * HD + 4 * cq + 1], acc.y);
                atomicAdd(&gout[(size_t)gcur * HD + 4 * cq + 2], acc.z);
                atomicAdd(&gout[(size_t)gcur * HD + 4 * cq + 3], acc.w);
            }
            acc = make_float4(0.f, 0.f, 0.f, 0.f);
            gcur = g;
        }
        float4 v = *(const float4*)(x + (size_t)r * HD + 4 * cq);
        acc.x += fmaxf(fmaf(v.x, s4.x, h4.x), 0.f);
        acc.y += fmaxf(fmaf(v.y, s4.y, h4.y), 0.f);
        acc.z += fmaxf(fmaf(v.z, s4.z, h4.z), 0.f);
        acc.w += fmaxf(fmaf(v.w, s4.w, h4.w), 0.f);
    }
    if (gcur >= 0) {
        atomicAdd(&gout[(size_t)gcur * HD + 4 * cq + 0], acc.x);
        atomicAdd(&gout[(size_t)gcur * HD + 4 * cq + 1], acc.y);
        atomicAdd(&gout[(size_t)gcur * HD + 4 * cq + 2], acc.z);
        atomicAdd(&gout[(size_t)gcur * HD + 4 * cq + 3], acc.w);
    }
}

// --------- fused head v4: 1024 thr; pre-split W + T14 prefetch (issue-early/write-late) --
__global__ __launch_bounds__(1024) void head_fused(const float* __restrict__ Gp,
                                                   const unsigned short* __restrict__ Whd,
                                                   const unsigned short* __restrict__ Wld,
                                                   const float* __restrict__ g0,
                                                   const float* __restrict__ b0,
                                                   const float* __restrict__ g1,
                                                   const float* __restrict__ b1,
                                                   const float* __restrict__ g2,
                                                   const float* __restrict__ b2,
                                                   const float* __restrict__ g3,
                                                   const float* __restrict__ b3,
                                                   const float* __restrict__ finW,
                                                   float* __restrict__ out) {
    const int AP = 132;
    __shared__ float A_lds[128 * AP];
    __shared__ unsigned short WhS[128 * WP];
    __shared__ unsigned short WlS[128 * WP];
    __shared__ float colS[HD], colQ[HD], scs[HD], shs[HD];
    int t = threadIdx.x;
    if (t < HD) { colS[t] = 0.f; colQ[t] = 0.f; scs[t] = 1.f; shs[t] = 0.f; }
#pragma unroll
    for (int i = 0; i < 4; i++) {
        int idx = t + i * 1024;
        int r = idx >> 5, cq = (idx & 31) * 4;
        *(float4*)&A_lds[r * AP + cq] = *(const float4*)(Gp + (size_t)r * HD + cq);
    }
    int sc_ = t >> 4;            // staging col, iter0 (0..63); iter1 is +64
    int sk_ = (t & 15) * 8;      // staging k-offset
    const float* gs[4] = {g0, g1, g2, g3};  // indexed only with unroll-constant s
    const float* bs[4] = {b0, b1, b2, b3};
    // prefetch stage 0 W into registers
    uint4 ph0 = *(const uint4*)(Whd + (size_t)sc_ * HD + sk_);
    uint4 ph1 = *(const uint4*)(Whd + (size_t)(sc_ + 64) * HD + sk_);
    uint4 pl0 = *(const uint4*)(Wld + (size_t)sc_ * HD + sk_);
    uint4 pl1 = *(const uint4*)(Wld + (size_t)(sc_ + 64) * HD + sk_);
    int w = t >> 6, lane = t & 63;
    int quad = lane >> 4, nl = lane & 15;
    int row0 = (w >> 2) * 32, col0 = (w & 3) * 32;
#pragma unroll
    for (int s = 0; s < 4; s++) {
        // write staged W (registers -> LDS)
        *(uint4*)(WhS + sc_ * WP + sk_) = ph0;
        *(uint4*)(WhS + (sc_ + 64) * WP + sk_) = ph1;
        *(uint4*)(WlS + sc_ * WP + sk_) = pl0;
        *(uint4*)(WlS + (sc_ + 64) * WP + sk_) = pl1;
        __syncthreads();  // W, scs/shs, A ready
        // issue next stage's W loads early: latency hides under MFMA phase
        if (s < 3) {
            const unsigned short* nh = Whd + (size_t)(s + 1) * 16384;
            const unsigned short* nl2 = Wld + (size_t)(s + 1) * 16384;
            ph0 = *(const uint4*)(nh + (size_t)sc_ * HD + sk_);
            ph1 = *(const uint4*)(nh + (size_t)(sc_ + 64) * HD + sk_);
            pl0 = *(const uint4*)(nl2 + (size_t)sc_ * HD + sk_);
            pl1 = *(const uint4*)(nl2 + (size_t)(sc_ + 64) * HD + sk_);
        }
        f32x4 acc[4];
#pragma unroll
        for (int i = 0; i < 4; i++) acc[i] = (f32x4){0.f, 0.f, 0.f, 0.f};
#pragma unroll
        for (int kc = 0; kc < 4; kc++) {
            int k0 = kc * 32 + quad * 8;
            float4 s0 = *(const float4*)&scs[k0], s1 = *(const float4*)&scs[k0 + 4];
            float4 t0 = *(const float4*)&shs[k0], t1 = *(const float4*)&shs[k0 + 4];
            bf16x8 a0h, a0l, a1h, a1l;
            {
                const float* ap = &A_lds[(row0 + nl) * AP + k0];
                float4 v0 = *(const float4*)ap;
                float4 v1 = *(const float4*)(ap + 4);
                float f0 = fmaxf(fmaf(v0.x, s0.x, t0.x), 0.f), f1 = fmaxf(fmaf(v0.y, s0.y, t0.y), 0.f);
                float f2 = fmaxf(fmaf(v0.z, s0.z, t0.z), 0.f), f3 = fmaxf(fmaf(v0.w, s0.w, t0.w), 0.f);
                float f4 = fmaxf(fmaf(v1.x, s1.x, t1.x), 0.f), f5 = fmaxf(fmaf(v1.y, s1.y, t1.y), 0.f);
                float f6 = fmaxf(fmaf(v1.z, s1.z, t1.z), 0.f), f7 = fmaxf(fmaf(v1.w, s1.w, t1.w), 0.f);
                unsigned h0, h1, h2, h3, l0, l1, l2, l3;
                split2(f0, f1, h0, l0); split2(f2, f3, h1, l1);
                split2(f4, f5, h2, l2); split2(f6, f7, h3, l3);
                a0h = __builtin_bit_cast(bf16x8, make_uint4(h0, h1, h2, h3));
                a0l = __builtin_bit_cast(bf16x8, make_uint4(l0, l1, l2, l3));
            }
            {
                const float* ap = &A_lds[(row0 + 16 + nl) * AP + k0];
                float4 v0 = *(const float4*)ap;
                float4 v1 = *(const float4*)(ap + 4);
                float f0 = fmaxf(fmaf(v0.x, s0.x, t0.x), 0.f), f1 = fmaxf(fmaf(v0.y, s0.y, t0.y), 0.f);
                float f2 = fmaxf(fmaf(v0.z, s0.z, t0.z), 0.f), f3 = fmaxf(fmaf(v0.w, s0.w, t0.w), 0.f);
                float f4 = fmaxf(fmaf(v1.x, s1.x, t1.x), 0.f), f5 = fmaxf(fmaf(v1.y, s1.y, t1.y), 0.f);
                float f6 = fmaxf(fmaf(v1.z, s1.z, t1.z), 0.f), f7 = fmaxf(fmaf(v1.w, s1.w, t1.w), 0.f);
                unsigned h0, h1, h2, h3, l0, l1, l2, l3;
                split2(f0, f1, h0, l0); split2(f2, f3, h1, l1);
                split2(f4, f5, h2, l2); split2(f6, f7, h3, l3);
                a1h = __builtin_bit_cast(bf16x8, make_uint4(h0, h1, h2, h3));
                a1l = __builtin_bit_cast(bf16x8, make_uint4(l0, l1, l2, l3));
            }
#pragma unroll
            for (int cc = 0; cc < 2; cc++) {
                int wof = (col0 + cc * 16 + nl) * WP + k0;
                bf16x8 bh = *(const bf16x8*)(WhS + wof);
                bf16x8 bl = *(const bf16x8*)(WlS + wof);
                acc[cc] = __builtin_amdgcn_mfma_f32_16x16x32_bf16(a0h, bh, acc[cc], 0, 0, 0);
                acc[cc] = __builtin_amdgcn_mfma_f32_16x16x32_bf16(a0l, bh, acc[cc], 0, 0, 0);
                acc[cc] = __builtin_amdgcn_mfma_f32_16x16x32_bf16(a0h, bl, acc[cc], 0, 0, 0);
                acc[2 + cc] = __builtin_amdgcn_mfma_f32_16x16x32_bf16(a1h, bh, acc[2 + cc], 0, 0, 0);
                acc[2 + cc] = __builtin_amdgcn_mfma_f32_16x16x32_bf16(a1l, bh, acc[2 + cc], 0, 0, 0);
                acc[2 + cc] = __builtin_amdgcn_mfma_f32_16x16x32_bf16(a1h, bl, acc[2 + cc], 0, 0, 0);
            }
        }
        __syncthreads();  // all A_lds + WhS reads done before overwrite
#pragma unroll
        for (int h = 0; h < 2; h++) {
            int baserow = row0 + h * 16 + quad * 4;
#pragma unroll
            for (int cc = 0; cc < 2; cc++) {
                int col = col0 + cc * 16 + nl;
                f32x4 v = acc[h * 2 + cc];
                float ss = 0.f, qq = 0.f;
#pragma unroll
                for (int r = 0; r < 4; r++) {
                    float val = v[r];
                    A_lds[(baserow + r) * AP + col] = val;
                    ss += val;
                    qq += val * val;
                }
                ss += __shfl_xor(ss, 16, 64);  ss += __shfl_xor(ss, 32, 64);
                qq += __shfl_xor(qq, 16, 64);  qq += __shfl_xor(qq, 32, 64);
                if (quad == 0) {
                    atomicAdd(&colS[col], ss);
                    atomicAdd(&colQ[col], qq);
                }
            }
        }
        __syncthreads();
        if (t < HD) {
            float m = colS[t] * (1.f / NG);
            float var = fmaxf(fmaf(colQ[t], 1.f / NG, -m * m), 0.f);
            float inv = rsqrtf(var + BN_EPS);
            float sc = gs[s][t] * inv;
            scs[t] = sc;
            shs[t] = fmaf(-m, sc, bs[s][t]);
            colS[t] = 0.f;
            colQ[t] = 0.f;
        }
        __syncthreads();
    }
    int r = t >> 3, g = t & 7;
    float ssum = 0.f;
#pragma unroll
    for (int j = 0; j < 16; j++) {
        int c = g * 16 + j;
        float v = fmaxf(fmaf(A_lds[r * AP + c], scs[c], shs[c]), 0.f);
        ssum += v * finW[c];
    }
    ssum += __shfl_xor(ssum, 1, 64);
    ssum += __shfl_xor(ssum, 2, 64);
    ssum += __shfl_xor(ssum, 4, 64);
    if (g == 0) out[r] = ssum;
}

extern "C" void kernel_launch(void* const* d_in, const int* in_sizes, int n_in,
                              void* d_out, int out_size, void* d_ws, size_t ws_size,
                              hipStream_t stream) {
    const int* x_ids = (const int*)d_in[0];
    const int* edge_index = (const int*)d_in[1];
    const int* batch = (const int*)d_in[2];
    const int* edge_attr = (const int*)d_in[3];
    const float* node_emb = (const float*)d_in[4];
    const float* edge_emb = (const float*)d_in[5];
    const float* eps = (const float*)d_in[6];
    const float* init_W1 = (const float*)d_in[7];
    const float* init_b1 = (const float*)d_in[8];
    const float* init_g1 = (const float*)d_in[9];
    const float* init_be1 = (const float*)d_in[10];
    const float* init_W2 = (const float*)d_in[11];
    const float* init_b2 = (const float*)d_in[12];
    const float* init_g2 = (const float*)d_in[13];
    const float* init_be2 = (const float*)d_in[14];
    const float* mp_W1 = (const float*)d_in[15];
    const float* mp_g1 = (const float*)d_in[16];
    const float* mp_be1 = (const float*)d_in[17];
    const float* mp_W2 = (const float*)d_in[18];
    const float* mp_g2 = (const float*)d_in[19];
    const float* mp_be2 = (const float*)d_in[20];
    const float* l1_W1 = (const float*)d_in[21];
    const float* l1_g1 = (const float*)d_in[22];
    const float* l1_b1 = (const float*)d_in[23];
    const float* l1_W2 = (const float*)d_in[24];
    const float* l1_g2 = (const float*)d_in[25];
    const float* l1_b2 = (const float*)d_in[26];
    const float* l2_W1 = (const float*)d_in[27];
    const float* l2_g1 = (const float*)d_in[28];
    const float* l2_b1 = (const float*)d_in[29];
    const float* l2_W2 = (const float*)d_in[30];
    const float* l2_g2 = (const float*)d_in[31];
    const float* l2_b2 = (const float*)d_in[32];
    const float* fin_W = (const float*)d_in[33];

    const int* e_src = edge_index;
    const int* e_dst = edge_index + NE;

    // workspace layout — SQ, Gp, deg contiguous -> ONE memset
    const size_t STG = (size_t)REP * 256;
    float* ws = (float*)d_ws;
    float* X = ws;
    float* Bbuf = X + (size_t)NN * HD;
    unsigned short* Yb = (unsigned short*)Bbuf;      // ALIAS (lifetime disjoint)
    unsigned short* Ah = (unsigned short*)(Bbuf + (size_t)NN * HD);
    unsigned short* Al = Ah + (size_t)NN * HD;
    float* SQ = (float*)(Al + (size_t)NN * HD);      // 14 stages } zeroed
    float* Gp = SQ + 14 * STG;                       //           } as one
    int* deg = (int*)(Gp + NG * HD);                 // pad 50048 } region
    int* barCnt = deg + 50016;                       // 5 barrier counters (zeroed, unused by deg)
    float* Hp = (float*)(deg + 50048);
    float* Hp2 = Hp + NG * HD;
    int* rowptr = (int*)(Hp2 + NG * HD);
    int* cursor = rowptr + 50048;
    int* blockSum = cursor + 50048;
    int* blockOff = blockSum + 64;
    int* bucketCursor = blockOff + 64;
    unsigned* csr = (unsigned*)(bucketCursor + NB);
    unsigned short* Wh = (unsigned short*)(csr + NE);   // 14 segs x 16384
    unsigned short* Wl = Wh + 229376;
    uint2* ebuf = (uint2*)(Wl + 229376);
    (void)Hp; (void)Hp2; (void)blockOff;

    const size_t zero_bytes = (14 * STG + NG * HD) * sizeof(float) + 50048 * sizeof(int);
    hipMemsetAsync(SQ, 0, zero_bytes, stream);

    const int SCAN_BLOCKS = (NN + 1023) / 1024;  // 49
    setup_kernel<<<7146, 256, 0, stream>>>(x_ids, node_emb, Yb, init_W1, init_W2, mp_W1,
                                           mp_W2, l1_W1, l1_W2, l2_W1, l2_W2,
                                           Wh, Wl, e_dst, deg);
    scan1_kernel<<<SCAN_BLOCKS, 1024, 0, stream>>>(deg, rowptr, blockSum);
    scan3_kernel<<<SCAN_BLOCKS, 1024, 0, stream>>>(rowptr, cursor, blockSum, bucketCursor,
                                                   SCAN_BLOCKS);
    bin_kernel<<<(NE + EPB - 1) / EPB, 256, 0, stream>>>(e_src, e_dst, edge_attr,
                                                         bucketCursor, ebuf);
    place_kernel<<<(NN + 127) / 128, 256, 0, stream>>>(ebuf, rowptr, cursor, csr);

    const int mfma_grid = (NN + 127) / 128;  // 391 (full 128-col blocks, 2 blocks/CU)
    const int ybn_grid = (NN + 63) / 64;     // 782
    for (int i = 0; i <= NL; i++) {
        const unsigned short* Wh1 = Wh + (size_t)(i == 0 ? 0 : 2 + (i - 1)) * 16384;
        const unsigned short* Wl1 = Wl + (size_t)(i == 0 ? 0 : 2 + (i - 1)) * 16384;
        const unsigned short* Wh2 = Wh + (size_t)(i == 0 ? 1 : 6 + (i - 1)) * 16384;
        const unsigned short* Wl2 = Wl + (size_t)(i == 0 ? 1 : 6 + (i - 1)) * 16384;
        const float* b1 = (i == 0) ? init_b1 : nullptr;
        const float* b2 = (i == 0) ? init_b2 : nullptr;
        const float* g1 = (i == 0) ? init_g1 : mp_g1 + (size_t)(i - 1) * HD;
        const float* be1 = (i == 0) ? init_be1 : mp_be1 + (size_t)(i - 1) * HD;
        const float* gp = (i == 1) ? init_g2 : mp_g2 + (size_t)(i - 2) * HD;
        const float* bp = (i == 1) ? init_be2 : mp_be2 + (size_t)(i - 2) * HD;
        float* Sprev = SQ + (size_t)(2 * i - 1) * STG;
        float* S1 = SQ + (size_t)(2 * i) * STG;
        float* S2 = SQ + (size_t)(2 * i + 1) * STG;

        if (i > 0) ybn_kernel<<<ybn_grid, 256, 0, stream>>>(X, Sprev, gp, bp, Yb);
        conv_kernel<<<(NN + 3) / 4, 256, 0, stream>>>(Yb, rowptr, csr, edge_emb, eps, i, Ah, Al);
        mm_fused<<<mfma_grid, 512, 0, stream>>>(Ah, Al, Wh1, Wl1, b1, Wh2, Wl2, b2,
                                                g1, be1, Bbuf, S1, X, S2,
                                                barCnt + i, mfma_grid);
    }

    float* S9 = SQ + 9 * STG;
    readout_kernel<<<(NN + 255) / 256, 256, 0, stream>>>(
        X, batch, S9, mp_g2 + 3 * HD, mp_be2 + 3 * HD, Gp);

    head_fused<<<1, 1024, 0, stream>>>(Gp, Wh + (size_t)10 * 16384, Wl + (size_t)10 * 16384,
                                       l1_g1, l1_b1, l1_g2, l1_b2,
                                       l2_g1, l2_b1, l2_g2, l2_b2,
                                       fin_W, (float*)d_out);
}

// Round 8
// 669.736 us; speedup vs baseline: 1.3369x; 1.3369x over previous
//
#include <hip/hip_runtime.h>

#define NN 50000
#define NE 800000
#define NG 128
#define HD 128
#define NL 4
#define BN_EPS 1e-5f
#define REP 32
#define WP 136
#define NB 392
#define EPB 4096

typedef __attribute__((ext_vector_type(8))) short bf16x8;
typedef __attribute__((ext_vector_type(4))) float f32x4;

__device__ __forceinline__ unsigned short f2bf(float f) {
    unsigned u = __float_as_uint(f);
    u += 0x7FFFu + ((u >> 16) & 1u);  // RNE
    return (unsigned short)(u >> 16);
}
__device__ __forceinline__ float bfval(unsigned short h) { return __uint_as_float((unsigned)h << 16); }
__device__ __forceinline__ float bflo(unsigned u) { return __uint_as_float(u << 16); }
__device__ __forceinline__ float bfhi(unsigned u) { return __uint_as_float(u & 0xFFFF0000u); }

__device__ __forceinline__ void split2(float a, float b, unsigned& hi, unsigned& lo) {
    unsigned ua = __float_as_uint(a), ub = __float_as_uint(b);
    hi = (ua >> 16) | (ub & 0xFFFF0000u);
    float ra = a - __uint_as_float(ua & 0xFFFF0000u);
    float rb = b - __uint_as_float(ub & 0xFFFF0000u);
    lo = (unsigned)f2bf(ra) | ((unsigned)f2bf(rb) << 16);
}
__device__ __forceinline__ unsigned pack2(float a, float b) {
    return (unsigned)f2bf(a) | ((unsigned)f2bf(b) << 16);
}

__device__ __forceinline__ void bn_pre(const float* SQbase,
                                       const float* gam, const float* bet,
                                       float inv_cnt, int t, float* scs, float* shs) {
    if (gam == nullptr) { scs[t] = 1.f; shs[t] = 0.f; return; }
    float s = 0.f, q = 0.f;
#pragma unroll
    for (int r = 0; r < REP; r++) {
        s += SQbase[r * 256 + t];
        q += SQbase[r * 256 + 128 + t];
    }
    float m = s * inv_cnt;
    float var = fmaxf(fmaf(q, inv_cnt, -m * m), 0.f);
    float inv = rsqrtf(var + BN_EPS);
    float sc = gam[t] * inv;
    scs[t] = sc;
    shs[t] = fmaf(-m, sc, bet[t]);
}

// -------- fused setup: embed (3125) | cvtw 14 segs incl. head W (896) | hist (3125) -----
__global__ __launch_bounds__(256) void setup_kernel(const int* __restrict__ ids,
                                                    const float* __restrict__ emb,
                                                    unsigned short* __restrict__ Yb,
                                                    const float* __restrict__ iw1,
                                                    const float* __restrict__ iw2,
                                                    const float* __restrict__ mw1,
                                                    const float* __restrict__ mw2,
                                                    const float* __restrict__ hw1,
                                                    const float* __restrict__ hw2,
                                                    const float* __restrict__ hw3,
                                                    const float* __restrict__ hw4,
                                                    unsigned short* __restrict__ Wh,
                                                    unsigned short* __restrict__ Wl,
                                                    const int* __restrict__ dst,
                                                    int* __restrict__ deg) {
    int b = blockIdx.x, t = threadIdx.x;
    if (b < 3125) {
        int i = b * 256 + t;
        if (i < NN * 16) {
            int node = i >> 4, g = i & 15;
            int id = ids[node];
            const float* p = emb + (size_t)id * HD + 8 * g;
            float4 a = *(const float4*)p;
            float4 bb = *(const float4*)(p + 4);
            uint4 o;
            o.x = pack2(a.x, a.y); o.y = pack2(a.z, a.w);
            o.z = pack2(bb.x, bb.y); o.w = pack2(bb.z, bb.w);
            *(uint4*)(Yb + (size_t)node * HD + 8 * g) = o;
        }
    } else if (b < 4021) {
        int i = (b - 3125) * 256 + t;
        if (i < 229376) {
            int seg = i >> 14, loc = i & 16383;
            float v;
            if (seg == 0)       v = iw1[loc];
            else if (seg == 1)  v = iw2[loc];
            else if (seg < 6)   v = mw1[(seg - 2) * 16384 + loc];
            else if (seg < 10)  v = mw2[(seg - 6) * 16384 + loc];
            else if (seg == 10) v = hw1[loc];
            else if (seg == 11) v = hw2[loc];
            else if (seg == 12) v = hw3[loc];
            else                v = hw4[loc];
            int k = loc >> 7, n = loc & 127;
            unsigned short h = f2bf(v);
            float r = v - bfval(h);
            Wh[seg * 16384 + n * 128 + k] = h;
            Wl[seg * 16384 + n * 128 + k] = f2bf(r);
        }
    } else {
        int e = (b - 4021) * 256 + t;
        if (e < NE) atomicAdd(&deg[dst[e]], 1);
    }
}

// ---------------- ybn: 64 rows/block (bn_pre amortized 4x) ----------------
__global__ __launch_bounds__(256) void ybn_kernel(const float* __restrict__ X,
                                                  const float* __restrict__ SQin,
                                                  const float* __restrict__ gam,
                                                  const float* __restrict__ bet,
                                                  unsigned short* __restrict__ Yb) {
    __shared__ float scs[HD], shs[HD];
    int t = threadIdx.x;
    if (t < HD) bn_pre(SQin, gam, bet, 1.f / NN, t, scs, shs);
    __syncthreads();
    int c8 = (t & 15) * 8;
    float4 s0 = *(const float4*)&scs[c8], s1 = *(const float4*)&scs[c8 + 4];
    float4 h0 = *(const float4*)&shs[c8], h1 = *(const float4*)&shs[c8 + 4];
#pragma unroll
    for (int ch = 0; ch < 4; ch++) {
        int row = blockIdx.x * 64 + ch * 16 + (t >> 4);
        if (row < NN) {
            const float* p = X + (size_t)row * HD + c8;
            float4 v0 = *(const float4*)p;
            float4 v1 = *(const float4*)(p + 4);
            float f0 = fmaxf(fmaf(v0.x, s0.x, h0.x), 0.f), f1 = fmaxf(fmaf(v0.y, s0.y, h0.y), 0.f);
            float f2 = fmaxf(fmaf(v0.z, s0.z, h0.z), 0.f), f3 = fmaxf(fmaf(v0.w, s0.w, h0.w), 0.f);
            float f4 = fmaxf(fmaf(v1.x, s1.x, h1.x), 0.f), f5 = fmaxf(fmaf(v1.y, s1.y, h1.y), 0.f);
            float f6 = fmaxf(fmaf(v1.z, s1.z, h1.z), 0.f), f7 = fmaxf(fmaf(v1.w, s1.w, h1.w), 0.f);
            uint4 o;
            o.x = pack2(f0, f1); o.y = pack2(f2, f3);
            o.z = pack2(f4, f5); o.w = pack2(f6, f7);
            *(uint4*)(Yb + (size_t)row * HD + c8) = o;
        }
    }
}

// ---------------- CSR scans (scan2 folded into scan3) ----------------
__global__ __launch_bounds__(1024) void scan1_kernel(const int* __restrict__ deg,
                                                     int* __restrict__ rowptr,
                                                     int* __restrict__ blockSum) {
    __shared__ int s[1024];
    int b = blockIdx.x, t = threadIdx.x;
    int i = b * 1024 + t;
    int v = (i < NN) ? deg[i] : 0;
    s[t] = v;
    __syncthreads();
    for (int off = 1; off < 1024; off <<= 1) {
        int u = (t >= off) ? s[t - off] : 0;
        __syncthreads();
        s[t] += u;
        __syncthreads();
    }
    if (i < NN) rowptr[i] = s[t] - v;
    if (t == 1023) blockSum[b] = s[1023];
}

__global__ __launch_bounds__(1024) void scan3_kernel(int* __restrict__ rowptr,
                                                     int* __restrict__ cursor,
                                                     const int* __restrict__ blockSum,
                                                     int* __restrict__ bucketCursor,
                                                     int nblocks) {
    __shared__ int sOff, sTot;
    int b = blockIdx.x, t = threadIdx.x;
    if (t < 64) {
        int orig = (t < nblocks) ? blockSum[t] : 0;
        int v = orig;
        for (int off = 1; off < 64; off <<= 1) {
            int u = __shfl_up(v, off, 64);
            if (t >= off) v += u;
        }
        if (t == b) sOff = v - orig;
        if (t == nblocks - 1) sTot = v;
    }
    __syncthreads();
    int i = b * 1024 + t;
    if (i < NN) {
        int r = rowptr[i] + sOff;
        rowptr[i] = r;
        cursor[i] = r;
        if ((i & 127) == 0) bucketCursor[i >> 7] = r;
    }
    if (b == nblocks - 1 && t == 0) rowptr[NN] = sTot;
}

// ---------------- bin ----------------
__global__ __launch_bounds__(256) void bin_kernel(const int* __restrict__ src,
                                                  const int* __restrict__ dst,
                                                  const int* __restrict__ attr,
                                                  int* __restrict__ bucketCursor,
                                                  uint2* __restrict__ ebuf) {
    __shared__ int cnt[512];
    __shared__ int sc[512], sc2[512];
    __shared__ int base[512];
    __shared__ int garr[NB];
    __shared__ int wof[NB];
    __shared__ uint2 stage[EPB];
    int t = threadIdx.x;
    int e0 = blockIdx.x * EPB;
    for (int i = t; i < 512; i += 256) cnt[i] = 0;
    __syncthreads();
    int myb[16]; unsigned myv[16]; int myd[16];
#pragma unroll
    for (int j = 0; j < 16; j++) {
        int e = e0 + t + j * 256;
        if (e < NE) {
            int d = dst[e];
            myd[j] = d;
            myv[j] = (unsigned)src[e] | ((unsigned)attr[e] << 16);
            myb[j] = d >> 7;
            atomicAdd(&cnt[myb[j]], 1);
        } else myb[j] = -1;
    }
    __syncthreads();
    for (int k = t; k < 512; k += 256) sc[k] = cnt[k];
    __syncthreads();
    int* sp = sc; int* dp = sc2;
    for (int off = 1; off < 512; off <<= 1) {
        for (int k = t; k < 512; k += 256) dp[k] = sp[k] + (k >= off ? sp[k - off] : 0);
        __syncthreads();
        int* tmp = sp; sp = dp; dp = tmp;
    }
    for (int k = t; k < 512; k += 256) base[k] = sp[k] - cnt[k];
    int total = sp[511];
    __syncthreads();
    for (int b = t; b < NB; b += 256) {
        wof[b] = 0;
        if (cnt[b] > 0) garr[b] = atomicAdd(&bucketCursor[b], cnt[b]);
    }
    __syncthreads();
#pragma unroll
    for (int j = 0; j < 16; j++) {
        if (myb[j] >= 0) {
            int slot = base[myb[j]] + atomicAdd(&wof[myb[j]], 1);
            stage[slot] = make_uint2(myv[j], (unsigned)myd[j]);
        }
    }
    __syncthreads();
    for (int i = t; i < total; i += 256) {
        uint2 u = stage[i];
        int b = (int)(u.y >> 7);
        ebuf[garr[b] + (i - base[b])] = u;
    }
}

// ---------------- place ----------------
__global__ __launch_bounds__(256) void place_kernel(const uint2* __restrict__ ebuf,
                                                    const int* __restrict__ rowptr,
                                                    int* __restrict__ cursor,
                                                    unsigned* __restrict__ csr) {
    int b = blockIdx.x;
    int n0 = b * 128;
    int n1 = n0 + 128; if (n1 > NN) n1 = NN;
    int es = rowptr[n0], ee = rowptr[n1];
    for (int i = es + threadIdx.x; i < ee; i += 256) {
        uint2 u = ebuf[i];
        int pos = atomicAdd(&cursor[u.y], 1);
        csr[pos] = u.x;
    }
}

// ---------------- GINE conv ----------------
__device__ __forceinline__ void gine_acc(const unsigned short* __restrict__ Yb,
                                         const float* __restrict__ elds,
                                         unsigned p, int cq, float mask, float* a) {
    uint4 q = *(const uint4*)(Yb + (size_t)(p & 0xFFFFu) * HD + 8 * cq);
    const float* ep = elds + (p >> 16) * HD + 8 * cq;
    float4 e0 = *(const float4*)ep;
    float4 e1 = *(const float4*)(ep + 4);
    a[0] += mask * fmaxf(bflo(q.x) + e0.x, 0.f);
    a[1] += mask * fmaxf(bfhi(q.x) + e0.y, 0.f);
    a[2] += mask * fmaxf(bflo(q.y) + e0.z, 0.f);
    a[3] += mask * fmaxf(bfhi(q.y) + e0.w, 0.f);
    a[4] += mask * fmaxf(bflo(q.z) + e1.x, 0.f);
    a[5] += mask * fmaxf(bfhi(q.z) + e1.y, 0.f);
    a[6] += mask * fmaxf(bflo(q.w) + e1.z, 0.f);
    a[7] += mask * fmaxf(bfhi(q.w) + e1.w, 0.f);
}

__global__ __launch_bounds__(256) void conv_kernel(const unsigned short* __restrict__ Yb,
                                                   const int* __restrict__ rowptr,
                                                   const unsigned* __restrict__ csr,
                                                   const float* __restrict__ edge_emb,
                                                   const float* __restrict__ eps, int layer,
                                                   unsigned short* __restrict__ Ah,
                                                   unsigned short* __restrict__ Al) {
    __shared__ float elds[8 * HD];
    int t = threadIdx.x;
    ((float4*)elds)[t] = ((const float4*)edge_emb)[t];
    __syncthreads();
    int wave = t >> 6, lane = t & 63;
    int node = blockIdx.x * 4 + wave;
    if (node >= NN) return;
    int sub = lane >> 4, cq = lane & 15;
    int lo = rowptr[node], hi = rowptr[node + 1];
    float a[8];
#pragma unroll
    for (int i = 0; i < 8; i++) a[i] = 0.f;
    for (int base = lo; base < hi; base += 64) {
        unsigned pl = 0;
        int cnt = hi - base; if (cnt > 64) cnt = 64;
        if (base + lane < hi) pl = csr[base + lane];
        int j = 0;
        for (; j + 16 <= cnt; j += 16) {
            unsigned pa = __shfl(pl, j + sub, 64);
            unsigned pb = __shfl(pl, j + 4 + sub, 64);
            unsigned pc = __shfl(pl, j + 8 + sub, 64);
            unsigned pd = __shfl(pl, j + 12 + sub, 64);
            gine_acc(Yb, elds, pa, cq, 1.f, a);
            gine_acc(Yb, elds, pb, cq, 1.f, a);
            gine_acc(Yb, elds, pc, cq, 1.f, a);
            gine_acc(Yb, elds, pd, cq, 1.f, a);
        }
        for (; j + 8 <= cnt; j += 8) {
            unsigned pa = __shfl(pl, j + sub, 64);
            unsigned pb = __shfl(pl, j + 4 + sub, 64);
            gine_acc(Yb, elds, pa, cq, 1.f, a);
            gine_acc(Yb, elds, pb, cq, 1.f, a);
        }
        for (; j < cnt; j += 4) {
            int je = j + sub;
            bool val = (je < cnt);
            unsigned p = __shfl(pl, val ? je : j, 64);
            gine_acc(Yb, elds, p, cq, val ? 1.f : 0.f, a);
        }
    }
#pragma unroll
    for (int i = 0; i < 8; i++) {
        a[i] += __shfl_xor(a[i], 16, 64);
        a[i] += __shfl_xor(a[i], 32, 64);
    }
    if (sub == 0) {
        float g = 1.f + eps[layer];
        uint4 q = *(const uint4*)(Yb + (size_t)node * HD + 8 * cq);
        float o0 = fmaf(g, bflo(q.x), a[0]), o1 = fmaf(g, bfhi(q.x), a[1]);
        float o2 = fmaf(g, bflo(q.y), a[2]), o3 = fmaf(g, bfhi(q.y), a[3]);
        float o4 = fmaf(g, bflo(q.z), a[4]), o5 = fmaf(g, bfhi(q.z), a[5]);
        float o6 = fmaf(g, bflo(q.w), a[6]), o7 = fmaf(g, bfhi(q.w), a[7]);
        uint4 H, L;
        split2(o0, o1, H.x, L.x);
        split2(o2, o3, H.y, L.y);
        split2(o4, o5, H.z, L.z);
        split2(o6, o7, H.w, L.w);
        *(uint4*)(Ah + (size_t)node * HD + 8 * cq) = H;
        *(uint4*)(Al + (size_t)node * HD + 8 * cq) = L;
    }
}

// ------- MFMA matmul, pre-split A (T14 prefetch), FULL 128-col W in LDS; 512 thr ---------
__global__ __launch_bounds__(512) void mm_mfma_pre(const unsigned short* __restrict__ Ah,
                                                   const unsigned short* __restrict__ Al,
                                                   const unsigned short* __restrict__ Wh,
                                                   const unsigned short* __restrict__ Wl,
                                                   const float* __restrict__ bias,
                                                   float* __restrict__ out,
                                                   float* __restrict__ SQout) {
    __shared__ unsigned short WhS[128 * WP];
    __shared__ unsigned short WlS[128 * WP];
    int t = threadIdx.x;
    int rowblk = blockIdx.x;
    int w = t >> 6, lane = t & 63;
    int quad = lane >> 4, nl = lane & 15;
    int row0 = rowblk * 128 + w * 16;
    int rA0 = row0 + nl;
    bool ok0 = rA0 < NN;
    // T14: issue A loads BEFORE W staging so HBM/L2 latency hides under staging+barrier
    bf16x8 pah[4], pal[4];
#pragma unroll
    for (int kc = 0; kc < 4; kc++) {
        int k0 = kc * 32 + quad * 8;
        pah[kc] = ok0 ? *(const bf16x8*)(Ah + (size_t)rA0 * HD + k0) : (bf16x8)0;
        pal[kc] = ok0 ? *(const bf16x8*)(Al + (size_t)rA0 * HD + k0) : (bf16x8)0;
    }
#pragma unroll
    for (int i = 0; i < 4; i++) {
        int idx = t + i * 512;
        int col = idx >> 4, kk = (idx & 15) * 8;
        *(uint4*)(WhS + col * WP + kk) = *(const uint4*)(Wh + (size_t)col * HD + kk);
        *(uint4*)(WlS + col * WP + kk) = *(const uint4*)(Wl + (size_t)col * HD + kk);
    }
    __syncthreads();
    f32x4 acc[8];
#pragma unroll
    for (int i = 0; i < 8; i++) acc[i] = (f32x4){0.f, 0.f, 0.f, 0.f};
#pragma unroll
    for (int kc = 0; kc < 4; kc++) {
        int k0 = kc * 32 + quad * 8;
        bf16x8 a0h = pah[kc];
        bf16x8 a0l = pal[kc];
#pragma unroll
        for (int c = 0; c < 8; c++) {
            int wof = (c * 16 + nl) * WP + k0;
            bf16x8 bh = *(const bf16x8*)(WhS + wof);
            bf16x8 bl = *(const bf16x8*)(WlS + wof);
            acc[c] = __builtin_amdgcn_mfma_f32_16x16x32_bf16(a0h, bh, acc[c], 0, 0, 0);
            acc[c] = __builtin_amdgcn_mfma_f32_16x16x32_bf16(a0l, bh, acc[c], 0, 0, 0);
            acc[c] = __builtin_amdgcn_mfma_f32_16x16x32_bf16(a0h, bl, acc[c], 0, 0, 0);
        }
    }
    int rep = (blockIdx.x & (REP - 1)) * 256;
    int baserow = row0 + quad * 4;
    if (rowblk * 128 + 128 <= NN) {
        // full tile: unguarded epilogue (wave-uniform branch)
#pragma unroll
        for (int c = 0; c < 8; c++) {
            int col = c * 16 + nl;
            float bv = bias ? bias[col] : 0.f;
            f32x4 v = acc[c];
            float s = 0.f, qq = 0.f;
#pragma unroll
            for (int r = 0; r < 4; r++) {
                float val = v[r] + bv;
                out[(size_t)(baserow + r) * HD + col] = val;
                s += val;
                qq += val * val;
            }
            s += __shfl_xor(s, 16, 64);  s += __shfl_xor(s, 32, 64);
            qq += __shfl_xor(qq, 16, 64); qq += __shfl_xor(qq, 32, 64);
            if (quad == 0) {
                atomicAdd(&SQout[rep + col], s);
                atomicAdd(&SQout[rep + 128 + col], qq);
            }
        }
    } else {
#pragma unroll
        for (int c = 0; c < 8; c++) {
            int col = c * 16 + nl;
            float bv = bias ? bias[col] : 0.f;
            f32x4 v = acc[c];
            float s = 0.f, qq = 0.f;
#pragma unroll
            for (int r = 0; r < 4; r++) {
                int grow = baserow + r;
                float val = v[r] + bv;
                if (grow < NN) {
                    out[(size_t)grow * HD + col] = val;
                    s += val;
                    qq += val * val;
                }
            }
            s += __shfl_xor(s, 16, 64);  s += __shfl_xor(s, 32, 64);
            qq += __shfl_xor(qq, 16, 64); qq += __shfl_xor(qq, 32, 64);
            if (quad == 0) {
                atomicAdd(&SQout[rep + col], s);
                atomicAdd(&SQout[rep + 128 + col], qq);
            }
        }
    }
}

// ------- MFMA matmul, fp32 A (T14 prefetch) + fused BN-act + split; 512 thr --------------
__global__ __launch_bounds__(512) void mm_mfma_act(const float* __restrict__ A,
                                                   const unsigned short* __restrict__ Wh,
                                                   const unsigned short* __restrict__ Wl,
                                                   const float* __restrict__ bias,
                                                   const float* __restrict__ SQin,
                                                   const float* __restrict__ gam,
                                                   const float* __restrict__ bet,
                                                   float* __restrict__ out,
                                                   float* __restrict__ SQout) {
    __shared__ unsigned short WhS[128 * WP];
    __shared__ unsigned short WlS[128 * WP];
    __shared__ float scs[HD], shs[HD];
    int t = threadIdx.x;
    int rowblk = blockIdx.x;
    int w = t >> 6, lane = t & 63;
    int quad = lane >> 4, nl = lane & 15;
    int row0 = rowblk * 128 + w * 16;
    int rA0 = row0 + nl;
    bool ok0 = rA0 < NN;
    // T14: issue A loads BEFORE bn_pre + W staging
    float4 pv0[4], pv1[4];
#pragma unroll
    for (int kc = 0; kc < 4; kc++) {
        int k0 = kc * 32 + quad * 8;
        pv0[kc] = ok0 ? *(const float4*)(A + (size_t)rA0 * HD + k0) : make_float4(0, 0, 0, 0);
        pv1[kc] = ok0 ? *(const float4*)(A + (size_t)rA0 * HD + k0 + 4) : make_float4(0, 0, 0, 0);
    }
    if (t < HD) bn_pre(SQin, gam, bet, 1.f / NN, t, scs, shs);
#pragma unroll
    for (int i = 0; i < 4; i++) {
        int idx = t + i * 512;
        int col = idx >> 4, kk = (idx & 15) * 8;
        *(uint4*)(WhS + col * WP + kk) = *(const uint4*)(Wh + (size_t)col * HD + kk);
        *(uint4*)(WlS + col * WP + kk) = *(const uint4*)(Wl + (size_t)col * HD + kk);
    }
    __syncthreads();
    f32x4 acc[8];
#pragma unroll
    for (int i = 0; i < 8; i++) acc[i] = (f32x4){0.f, 0.f, 0.f, 0.f};
#pragma unroll
    for (int kc = 0; kc < 4; kc++) {
        int k0 = kc * 32 + quad * 8;
        float4 s0 = *(const float4*)&scs[k0], s1 = *(const float4*)&scs[k0 + 4];
        float4 t0 = *(const float4*)&shs[k0], t1 = *(const float4*)&shs[k0 + 4];
        bf16x8 a0h, a0l;
        {
            float4 v0 = pv0[kc];
            float4 v1 = pv1[kc];
            float f0 = fmaxf(fmaf(v0.x, s0.x, t0.x), 0.f), f1 = fmaxf(fmaf(v0.y, s0.y, t0.y), 0.f);
            float f2 = fmaxf(fmaf(v0.z, s0.z, t0.z), 0.f), f3 = fmaxf(fmaf(v0.w, s0.w, t0.w), 0.f);
            float f4 = fmaxf(fmaf(v1.x, s1.x, t1.x), 0.f), f5 = fmaxf(fmaf(v1.y, s1.y, t1.y), 0.f);
            float f6 = fmaxf(fmaf(v1.z, s1.z, t1.z), 0.f), f7 = fmaxf(fmaf(v1.w, s1.w, t1.w), 0.f);
            if (!ok0) { f0 = f1 = f2 = f3 = f4 = f5 = f6 = f7 = 0.f; }
            unsigned h0, h1, h2, h3, l0, l1, l2, l3;
            split2(f0, f1, h0, l0); split2(f2, f3, h1, l1);
            split2(f4, f5, h2, l2); split2(f6, f7, h3, l3);
            a0h = __builtin_bit_cast(bf16x8, make_uint4(h0, h1, h2, h3));
            a0l = __builtin_bit_cast(bf16x8, make_uint4(l0, l1, l2, l3));
        }
#pragma unroll
        for (int c = 0; c < 8; c++) {
            int wof = (c * 16 + nl) * WP + k0;
            bf16x8 bh = *(const bf16x8*)(WhS + wof);
            bf16x8 bl = *(const bf16x8*)(WlS + wof);
            acc[c] = __builtin_amdgcn_mfma_f32_16x16x32_bf16(a0h, bh, acc[c], 0, 0, 0);
            acc[c] = __builtin_amdgcn_mfma_f32_16x16x32_bf16(a0l, bh, acc[c], 0, 0, 0);
            acc[c] = __builtin_amdgcn_mfma_f32_16x16x32_bf16(a0h, bl, acc[c], 0, 0, 0);
        }
    }
    int rep = (blockIdx.x & (REP - 1)) * 256;
    int baserow = row0 + quad * 4;
    if (rowblk * 128 + 128 <= NN) {
#pragma unroll
        for (int c = 0; c < 8; c++) {
            int col = c * 16 + nl;
            float bv = bias ? bias[col] : 0.f;
            f32x4 v = acc[c];
            float s = 0.f, qq = 0.f;
#pragma unroll
            for (int r = 0; r < 4; r++) {
                float val = v[r] + bv;
                out[(size_t)(baserow + r) * HD + col] = val;
                s += val;
                qq += val * val;
            }
            s += __shfl_xor(s, 16, 64);  s += __shfl_xor(s, 32, 64);
            qq += __shfl_xor(qq, 16, 64); qq += __shfl_xor(qq, 32, 64);
            if (quad == 0) {
                atomicAdd(&SQout[rep + col], s);
                atomicAdd(&SQout[rep + 128 + col], qq);
            }
        }
    } else {
#pragma unroll
        for (int c = 0; c < 8; c++) {
            int col = c * 16 + nl;
            float bv = bias ? bias[col] : 0.f;
            f32x4 v = acc[c];
            float s = 0.f, qq = 0.f;
#pragma unroll
            for (int r = 0; r < 4; r++) {
                int grow = baserow + r;
                float val = v[r] + bv;
                if (grow < NN) {
                    out[(size_t)grow * HD + col] = val;
                    s += val;
                    qq += val * val;
                }
            }
            s += __shfl_xor(s, 16, 64);  s += __shfl_xor(s, 32, 64);
            qq += __shfl_xor(qq, 16, 64); qq += __shfl_xor(qq, 32, 64);
            if (quad == 0) {
                atomicAdd(&SQout[rep + col], s);
                atomicAdd(&SQout[rep + 128 + col], qq);
            }
        }
    }
}

// ---------------- readout ----------------
__global__ __launch_bounds__(256) void readout_kernel(const float* __restrict__ x,
                                                      const int* __restrict__ batch,
                                                      const float* __restrict__ SQin,
                                                      const float* __restrict__ gam,
                                                      const float* __restrict__ bet,
                                                      float* __restrict__ gout) {
    __shared__ int bat[256];
    __shared__ float scs[HD], shs[HD];
    int t = threadIdx.x;
    int rq = t >> 5, cq = t & 31;
    int r0 = blockIdx.x * 256;
    int i = r0 + t;
    bat[t] = (i < NN) ? batch[i] : -1;
    if (t < HD) bn_pre(SQin, gam, bet, 1.f / NN, t, scs, shs);
    __syncthreads();
    float4 s4 = *(const float4*)&scs[4 * cq];
    float4 h4 = *(const float4*)&shs[4 * cq];
    float4 acc = make_float4(0.f, 0.f, 0.f, 0.f);
    int gcur = -1;
    for (int j = rq; j < 256; j += 8) {
        int r = r0 + j;
        if (r >= NN) break;
        int g = bat[j];
        if (g != gcur) {
            if (gcur >= 0) {
                atomicAdd(&gout[(size_t)gcur * HD + 4 * cq + 0], acc.x);
                atomicAdd(&gout[(size_t)gcur * HD + 4 * cq + 1], acc.y);
                atomicAdd(&gout[(size_t)gcur * HD + 4 * cq + 2], acc.z);
                atomicAdd(&gout[(size_t)gcur * HD + 4 * cq + 3], acc.w);
            }
            acc = make_float4(0.f, 0.f, 0.f, 0.f);
            gcur = g;
        }
        float4 v = *(const float4*)(x + (size_t)r * HD + 4 * cq);
        acc.x += fmaxf(fmaf(v.x, s4.x, h4.x), 0.f);
        acc.y += fmaxf(fmaf(v.y, s4.y, h4.y), 0.f);
        acc.z += fmaxf(fmaf(v.z, s4.z, h4.z), 0.f);
        acc.w += fmaxf(fmaf(v.w, s4.w, h4.w), 0.f);
    }
    if (gcur >= 0) {
        atomicAdd(&gout[(size_t)gcur * HD + 4 * cq + 0], acc.x);
        atomicAdd(&gout[(size_t)gcur * HD + 4 * cq + 1], acc.y);
        atomicAdd(&gout[(size_t)gcur * HD + 4 * cq + 2], acc.z);
        atomicAdd(&gout[(size_t)gcur * HD + 4 * cq + 3], acc.w);
    }
}

// --------- fused head v4: 1024 thr; pre-split W + T14 prefetch (issue-early/write-late) --
__global__ __launch_bounds__(1024) void head_fused(const float* __restrict__ Gp,
                                                   const unsigned short* __restrict__ Whd,
                                                   const unsigned short* __restrict__ Wld,
                                                   const float* __restrict__ g0,
                                                   const float* __restrict__ b0,
                                                   const float* __restrict__ g1,
                                                   const float* __restrict__ b1,
                                                   const float* __restrict__ g2,
                                                   const float* __restrict__ b2,
                                                   const float* __restrict__ g3,
                                                   const float* __restrict__ b3,
                                                   const float* __restrict__ finW,
                                                   float* __restrict__ out) {
    const int AP = 132;
    __shared__ float A_lds[128 * AP];
    __shared__ unsigned short WhS[128 * WP];
    __shared__ unsigned short WlS[128 * WP];
    __shared__ float colS[HD], colQ[HD], scs[HD], shs[HD];
    int t = threadIdx.x;
    if (t < HD) { colS[t] = 0.f; colQ[t] = 0.f; scs[t] = 1.f; shs[t] = 0.f; }
#pragma unroll
    for (int i = 0; i < 4; i++) {
        int idx = t + i * 1024;
        int r = idx >> 5, cq = (idx & 31) * 4;
        *(float4*)&A_lds[r * AP + cq] = *(const float4*)(Gp + (size_t)r * HD + cq);
    }
    int sc_ = t >> 4;            // staging col, iter0 (0..63); iter1 is +64
    int sk_ = (t & 15) * 8;      // staging k-offset
    const float* gs[4] = {g0, g1, g2, g3};  // indexed only with unroll-constant s
    const float* bs[4] = {b0, b1, b2, b3};
    // prefetch stage 0 W into registers
    uint4 ph0 = *(const uint4*)(Whd + (size_t)sc_ * HD + sk_);
    uint4 ph1 = *(const uint4*)(Whd + (size_t)(sc_ + 64) * HD + sk_);
    uint4 pl0 = *(const uint4*)(Wld + (size_t)sc_ * HD + sk_);
    uint4 pl1 = *(const uint4*)(Wld + (size_t)(sc_ + 64) * HD + sk_);
    int w = t >> 6, lane = t & 63;
    int quad = lane >> 4, nl = lane & 15;
    int row0 = (w >> 2) * 32, col0 = (w & 3) * 32;
#pragma unroll
    for (int s = 0; s < 4; s++) {
        // write staged W (registers -> LDS)
        *(uint4*)(WhS + sc_ * WP + sk_) = ph0;
        *(uint4*)(WhS + (sc_ + 64) * WP + sk_) = ph1;
        *(uint4*)(WlS + sc_ * WP + sk_) = pl0;
        *(uint4*)(WlS + (sc_ + 64) * WP + sk_) = pl1;
        __syncthreads();  // W, scs/shs, A ready
        // issue next stage's W loads early: latency hides under MFMA phase
        if (s < 3) {
            const unsigned short* nh = Whd + (size_t)(s + 1) * 16384;
            const unsigned short* nl2 = Wld + (size_t)(s + 1) * 16384;
            ph0 = *(const uint4*)(nh + (size_t)sc_ * HD + sk_);
            ph1 = *(const uint4*)(nh + (size_t)(sc_ + 64) * HD + sk_);
            pl0 = *(const uint4*)(nl2 + (size_t)sc_ * HD + sk_);
            pl1 = *(const uint4*)(nl2 + (size_t)(sc_ + 64) * HD + sk_);
        }
        f32x4 acc[4];
#pragma unroll
        for (int i = 0; i < 4; i++) acc[i] = (f32x4){0.f, 0.f, 0.f, 0.f};
#pragma unroll
        for (int kc = 0; kc < 4; kc++) {
            int k0 = kc * 32 + quad * 8;
            float4 s0 = *(const float4*)&scs[k0], s1 = *(const float4*)&scs[k0 + 4];
            float4 t0 = *(const float4*)&shs[k0], t1 = *(const float4*)&shs[k0 + 4];
            bf16x8 a0h, a0l, a1h, a1l;
            {
                const float* ap = &A_lds[(row0 + nl) * AP + k0];
                float4 v0 = *(const float4*)ap;
                float4 v1 = *(const float4*)(ap + 4);
                float f0 = fmaxf(fmaf(v0.x, s0.x, t0.x), 0.f), f1 = fmaxf(fmaf(v0.y, s0.y, t0.y), 0.f);
                float f2 = fmaxf(fmaf(v0.z, s0.z, t0.z), 0.f), f3 = fmaxf(fmaf(v0.w, s0.w, t0.w), 0.f);
                float f4 = fmaxf(fmaf(v1.x, s1.x, t1.x), 0.f), f5 = fmaxf(fmaf(v1.y, s1.y, t1.y), 0.f);
                float f6 = fmaxf(fmaf(v1.z, s1.z, t1.z), 0.f), f7 = fmaxf(fmaf(v1.w, s1.w, t1.w), 0.f);
                unsigned h0, h1, h2, h3, l0, l1, l2, l3;
                split2(f0, f1, h0, l0); split2(f2, f3, h1, l1);
                split2(f4, f5, h2, l2); split2(f6, f7, h3, l3);
                a0h = __builtin_bit_cast(bf16x8, make_uint4(h0, h1, h2, h3));
                a0l = __builtin_bit_cast(bf16x8, make_uint4(l0, l1, l2, l3));
            }
            {
                const float* ap = &A_lds[(row0 + 16 + nl) * AP + k0];
                float4 v0 = *(const float4*)ap;
                float4 v1 = *(const float4*)(ap + 4);
                float f0 = fmaxf(fmaf(v0.x, s0.x, t0.x), 0.f), f1 = fmaxf(fmaf(v0.y, s0.y, t0.y), 0.f);
                float f2 = fmaxf(fmaf(v0.z, s0.z, t0.z), 0.f), f3 = fmaxf(fmaf(v0.w, s0.w, t0.w), 0.f);
                float f4 = fmaxf(fmaf(v1.x, s1.x, t1.x), 0.f), f5 = fmaxf(fmaf(v1.y, s1.y, t1.y), 0.f);
                float f6 = fmaxf(fmaf(v1.z, s1.z, t1.z), 0.f), f7 = fmaxf(fmaf(v1.w, s1.w, t1.w), 0.f);
                unsigned h0, h1, h2, h3, l0, l1, l2, l3;
                split2(f0, f1, h0, l0); split2(f2, f3, h1, l1);
                split2(f4, f5, h2, l2); split2(f6, f7, h3, l3);
                a1h = __builtin_bit_cast(bf16x8, make_uint4(h0, h1, h2, h3));
                a1l = __builtin_bit_cast(bf16x8, make_uint4(l0, l1, l2, l3));
            }
#pragma unroll
            for (int cc = 0; cc < 2; cc++) {
                int wof = (col0 + cc * 16 + nl) * WP + k0;
                bf16x8 bh = *(const bf16x8*)(WhS + wof);
                bf16x8 bl = *(const bf16x8*)(WlS + wof);
                acc[cc] = __builtin_amdgcn_mfma_f32_16x16x32_bf16(a0h, bh, acc[cc], 0, 0, 0);
                acc[cc] = __builtin_amdgcn_mfma_f32_16x16x32_bf16(a0l, bh, acc[cc], 0, 0, 0);
                acc[cc] = __builtin_amdgcn_mfma_f32_16x16x32_bf16(a0h, bl, acc[cc], 0, 0, 0);
                acc[2 + cc] = __builtin_amdgcn_mfma_f32_16x16x32_bf16(a1h, bh, acc[2 + cc], 0, 0, 0);
                acc[2 + cc] = __builtin_amdgcn_mfma_f32_16x16x32_bf16(a1l, bh, acc[2 + cc], 0, 0, 0);
                acc[2 + cc] = __builtin_amdgcn_mfma_f32_16x16x32_bf16(a1h, bl, acc[2 + cc], 0, 0, 0);
            }
        }
        __syncthreads();  // all A_lds + WhS reads done before overwrite
#pragma unroll
        for (int h = 0; h < 2; h++) {
            int baserow = row0 + h * 16 + quad * 4;
#pragma unroll
            for (int cc = 0; cc < 2; cc++) {
                int col = col0 + cc * 16 + nl;
                f32x4 v = acc[h * 2 + cc];
                float ss = 0.f, qq = 0.f;
#pragma unroll
                for (int r = 0; r < 4; r++) {
                    float val = v[r];
                    A_lds[(baserow + r) * AP + col] = val;
                    ss += val;
                    qq += val * val;
                }
                ss += __shfl_xor(ss, 16, 64);  ss += __shfl_xor(ss, 32, 64);
                qq += __shfl_xor(qq, 16, 64);  qq += __shfl_xor(qq, 32, 64);
                if (quad == 0) {
                    atomicAdd(&colS[col], ss);
                    atomicAdd(&colQ[col], qq);
                }
            }
        }
        __syncthreads();
        if (t < HD) {
            float m = colS[t] * (1.f / NG);
            float var = fmaxf(fmaf(colQ[t], 1.f / NG, -m * m), 0.f);
            float inv = rsqrtf(var + BN_EPS);
            float sc = gs[s][t] * inv;
            scs[t] = sc;
            shs[t] = fmaf(-m, sc, bs[s][t]);
            colS[t] = 0.f;
            colQ[t] = 0.f;
        }
        __syncthreads();
    }
    int r = t >> 3, g = t & 7;
    float ssum = 0.f;
#pragma unroll
    for (int j = 0; j < 16; j++) {
        int c = g * 16 + j;
        float v = fmaxf(fmaf(A_lds[r * AP + c], scs[c], shs[c]), 0.f);
        ssum += v * finW[c];
    }
    ssum += __shfl_xor(ssum, 1, 64);
    ssum += __shfl_xor(ssum, 2, 64);
    ssum += __shfl_xor(ssum, 4, 64);
    if (g == 0) out[r] = ssum;
}

extern "C" void kernel_launch(void* const* d_in, const int* in_sizes, int n_in,
                              void* d_out, int out_size, void* d_ws, size_t ws_size,
                              hipStream_t stream) {
    const int* x_ids = (const int*)d_in[0];
    const int* edge_index = (const int*)d_in[1];
    const int* batch = (const int*)d_in[2];
    const int* edge_attr = (const int*)d_in[3];
    const float* node_emb = (const float*)d_in[4];
    const float* edge_emb = (const float*)d_in[5];
    const float* eps = (const float*)d_in[6];
    const float* init_W1 = (const float*)d_in[7];
    const float* init_b1 = (const float*)d_in[8];
    const float* init_g1 = (const float*)d_in[9];
    const float* init_be1 = (const float*)d_in[10];
    const float* init_W2 = (const float*)d_in[11];
    const float* init_b2 = (const float*)d_in[12];
    const float* init_g2 = (const float*)d_in[13];
    const float* init_be2 = (const float*)d_in[14];
    const float* mp_W1 = (const float*)d_in[15];
    const float* mp_g1 = (const float*)d_in[16];
    const float* mp_be1 = (const float*)d_in[17];
    const float* mp_W2 = (const float*)d_in[18];
    const float* mp_g2 = (const float*)d_in[19];
    const float* mp_be2 = (const float*)d_in[20];
    const float* l1_W1 = (const float*)d_in[21];
    const float* l1_g1 = (const float*)d_in[22];
    const float* l1_b1 = (const float*)d_in[23];
    const float* l1_W2 = (const float*)d_in[24];
    const float* l1_g2 = (const float*)d_in[25];
    const float* l1_b2 = (const float*)d_in[26];
    const float* l2_W1 = (const float*)d_in[27];
    const float* l2_g1 = (const float*)d_in[28];
    const float* l2_b1 = (const float*)d_in[29];
    const float* l2_W2 = (const float*)d_in[30];
    const float* l2_g2 = (const float*)d_in[31];
    const float* l2_b2 = (const float*)d_in[32];
    const float* fin_W = (const float*)d_in[33];

    const int* e_src = edge_index;
    const int* e_dst = edge_index + NE;

    // workspace layout — SQ, Gp, deg contiguous -> ONE memset
    const size_t STG = (size_t)REP * 256;
    float* ws = (float*)d_ws;
    float* X = ws;
    float* Bbuf = X + (size_t)NN * HD;
    unsigned short* Yb = (unsigned short*)Bbuf;      // ALIAS (lifetime disjoint)
    unsigned short* Ah = (unsigned short*)(Bbuf + (size_t)NN * HD);
    unsigned short* Al = Ah + (size_t)NN * HD;
    float* SQ = (float*)(Al + (size_t)NN * HD);      // 14 stages } zeroed
    float* Gp = SQ + 14 * STG;                       //           } as one
    int* deg = (int*)(Gp + NG * HD);                 // pad 50048 } region
    float* Hp = (float*)(deg + 50048);
    float* Hp2 = Hp + NG * HD;
    int* rowptr = (int*)(Hp2 + NG * HD);
    int* cursor = rowptr + 50048;
    int* blockSum = cursor + 50048;
    int* blockOff = blockSum + 64;
    int* bucketCursor = blockOff + 64;
    unsigned* csr = (unsigned*)(bucketCursor + NB);
    unsigned short* Wh = (unsigned short*)(csr + NE);   // 14 segs x 16384
    unsigned short* Wl = Wh + 229376;
    uint2* ebuf = (uint2*)(Wl + 229376);
    (void)Hp; (void)Hp2; (void)blockOff;

    const size_t zero_bytes = (14 * STG + NG * HD) * sizeof(float) + 50048 * sizeof(int);
    hipMemsetAsync(SQ, 0, zero_bytes, stream);

    const int SCAN_BLOCKS = (NN + 1023) / 1024;  // 49
    setup_kernel<<<7146, 256, 0, stream>>>(x_ids, node_emb, Yb, init_W1, init_W2, mp_W1,
                                           mp_W2, l1_W1, l1_W2, l2_W1, l2_W2,
                                           Wh, Wl, e_dst, deg);
    scan1_kernel<<<SCAN_BLOCKS, 1024, 0, stream>>>(deg, rowptr, blockSum);
    scan3_kernel<<<SCAN_BLOCKS, 1024, 0, stream>>>(rowptr, cursor, blockSum, bucketCursor,
                                                   SCAN_BLOCKS);
    bin_kernel<<<(NE + EPB - 1) / EPB, 256, 0, stream>>>(e_src, e_dst, edge_attr,
                                                         bucketCursor, ebuf);
    place_kernel<<<(NN + 127) / 128, 256, 0, stream>>>(ebuf, rowptr, cursor, csr);

    const int mfma_grid = (NN + 127) / 128;  // 391 (full 128-col blocks)
    const int ybn_grid = (NN + 63) / 64;     // 782
    for (int i = 0; i <= NL; i++) {
        const unsigned short* Wh1 = Wh + (size_t)(i == 0 ? 0 : 2 + (i - 1)) * 16384;
        const unsigned short* Wl1 = Wl + (size_t)(i == 0 ? 0 : 2 + (i - 1)) * 16384;
        const unsigned short* Wh2 = Wh + (size_t)(i == 0 ? 1 : 6 + (i - 1)) * 16384;
        const unsigned short* Wl2 = Wl + (size_t)(i == 0 ? 1 : 6 + (i - 1)) * 16384;
        const float* b1 = (i == 0) ? init_b1 : nullptr;
        const float* b2 = (i == 0) ? init_b2 : nullptr;
        const float* g1 = (i == 0) ? init_g1 : mp_g1 + (size_t)(i - 1) * HD;
        const float* be1 = (i == 0) ? init_be1 : mp_be1 + (size_t)(i - 1) * HD;
        const float* gp = (i == 1) ? init_g2 : mp_g2 + (size_t)(i - 2) * HD;
        const float* bp = (i == 1) ? init_be2 : mp_be2 + (size_t)(i - 2) * HD;
        float* Sprev = SQ + (size_t)(2 * i - 1) * STG;
        float* S1 = SQ + (size_t)(2 * i) * STG;
        float* S2 = SQ + (size_t)(2 * i + 1) * STG;

        if (i > 0) ybn_kernel<<<ybn_grid, 256, 0, stream>>>(X, Sprev, gp, bp, Yb);
        conv_kernel<<<(NN + 3) / 4, 256, 0, stream>>>(Yb, rowptr, csr, edge_emb, eps, i, Ah, Al);
        mm_mfma_pre<<<mfma_grid, 512, 0, stream>>>(Ah, Al, Wh1, Wl1, b1, Bbuf, S1);
        mm_mfma_act<<<mfma_grid, 512, 0, stream>>>(Bbuf, Wh2, Wl2, b2, S1, g1, be1, X, S2);
    }

    float* S9 = SQ + 9 * STG;
    readout_kernel<<<(NN + 255) / 256, 256, 0, stream>>>(
        X, batch, S9, mp_g2 + 3 * HD, mp_be2 + 3 * HD, Gp);

    head_fused<<<1, 1024, 0, stream>>>(Gp, Wh + (size_t)10 * 16384, Wl + (size_t)10 * 16384,
                                       l1_g1, l1_b1, l1_g2, l1_b2,
                                       l2_g1, l2_b1, l2_g2, l2_b2,
                                       fin_W, (float*)d_out);
}

// Round 10
// 666.532 us; speedup vs baseline: 1.3433x; 1.0048x over previous
//
#include <hip/hip_runtime.h>

#define NN 50000
#define NE 800000
#define NG 128
#define HD 128
#define NL 4
#define BN_EPS 1e-5f
#define REP 32
#define WP 136
#define NB 392
#define EPB 4096

typedef __attribute__((ext_vector_type(8))) short bf16x8;
typedef __attribute__((ext_vector_type(4))) float f32x4;

__device__ __forceinline__ unsigned short f2bf(float f) {
    unsigned u = __float_as_uint(f);
    u += 0x7FFFu + ((u >> 16) & 1u);  // RNE
    return (unsigned short)(u >> 16);
}
__device__ __forceinline__ float bfval(unsigned short h) { return __uint_as_float((unsigned)h << 16); }
__device__ __forceinline__ float bflo(unsigned u) { return __uint_as_float(u << 16); }
__device__ __forceinline__ float bfhi(unsigned u) { return __uint_as_float(u & 0xFFFF0000u); }

__device__ __forceinline__ void split2(float a, float b, unsigned& hi, unsigned& lo) {
    unsigned ua = __float_as_uint(a), ub = __float_as_uint(b);
    hi = (ua >> 16) | (ub & 0xFFFF0000u);
    float ra = a - __uint_as_float(ua & 0xFFFF0000u);
    float rb = b - __uint_as_float(ub & 0xFFFF0000u);
    lo = (unsigned)f2bf(ra) | ((unsigned)f2bf(rb) << 16);
}
__device__ __forceinline__ unsigned pack2(float a, float b) {
    return (unsigned)f2bf(a) | ((unsigned)f2bf(b) << 16);
}

__device__ __forceinline__ void bn_pre(const float* SQbase,
                                       const float* gam, const float* bet,
                                       float inv_cnt, int t, float* scs, float* shs) {
    if (gam == nullptr) { scs[t] = 1.f; shs[t] = 0.f; return; }
    float s = 0.f, q = 0.f;
#pragma unroll
    for (int r = 0; r < REP; r++) {
        s += SQbase[r * 256 + t];
        q += SQbase[r * 256 + 128 + t];
    }
    float m = s * inv_cnt;
    float var = fmaxf(fmaf(q, inv_cnt, -m * m), 0.f);
    float inv = rsqrtf(var + BN_EPS);
    float sc = gam[t] * inv;
    scs[t] = sc;
    shs[t] = fmaf(-m, sc, bet[t]);
}

// -------- fused setup: embed (3125) | cvtw 14 segs incl. head W (896) | hist (3125) -----
__global__ __launch_bounds__(256) void setup_kernel(const int* __restrict__ ids,
                                                    const float* __restrict__ emb,
                                                    unsigned short* __restrict__ Yb,
                                                    const float* __restrict__ iw1,
                                                    const float* __restrict__ iw2,
                                                    const float* __restrict__ mw1,
                                                    const float* __restrict__ mw2,
                                                    const float* __restrict__ hw1,
                                                    const float* __restrict__ hw2,
                                                    const float* __restrict__ hw3,
                                                    const float* __restrict__ hw4,
                                                    unsigned short* __restrict__ Wh,
                                                    unsigned short* __restrict__ Wl,
                                                    const int* __restrict__ dst,
                                                    int* __restrict__ deg) {
    int b = blockIdx.x, t = threadIdx.x;
    if (b < 3125) {
        int i = b * 256 + t;
        if (i < NN * 16) {
            int node = i >> 4, g = i & 15;
            int id = ids[node];
            const float* p = emb + (size_t)id * HD + 8 * g;
            float4 a = *(const float4*)p;
            float4 bb = *(const float4*)(p + 4);
            uint4 o;
            o.x = pack2(a.x, a.y); o.y = pack2(a.z, a.w);
            o.z = pack2(bb.x, bb.y); o.w = pack2(bb.z, bb.w);
            *(uint4*)(Yb + (size_t)node * HD + 8 * g) = o;
        }
    } else if (b < 4021) {
        int i = (b - 3125) * 256 + t;
        if (i < 229376) {
            int seg = i >> 14, loc = i & 16383;
            float v;
            if (seg == 0)       v = iw1[loc];
            else if (seg == 1)  v = iw2[loc];
            else if (seg < 6)   v = mw1[(seg - 2) * 16384 + loc];
            else if (seg < 10)  v = mw2[(seg - 6) * 16384 + loc];
            else if (seg == 10) v = hw1[loc];
            else if (seg == 11) v = hw2[loc];
            else if (seg == 12) v = hw3[loc];
            else                v = hw4[loc];
            int k = loc >> 7, n = loc & 127;
            unsigned short h = f2bf(v);
            float r = v - bfval(h);
            Wh[seg * 16384 + n * 128 + k] = h;
            Wl[seg * 16384 + n * 128 + k] = f2bf(r);
        }
    } else {
        int e = (b - 4021) * 256 + t;
        if (e < NE) atomicAdd(&deg[dst[e]], 1);
    }
}

// ------- ybn: fp32 X input, 128 rows/block (bn_pre amortized 8x) -------------------------
__global__ __launch_bounds__(256) void ybn_kernel(const float* __restrict__ X,
                                                  const float* __restrict__ SQin,
                                                  const float* __restrict__ gam,
                                                  const float* __restrict__ bet,
                                                  unsigned short* __restrict__ Yb) {
    __shared__ float scs[HD], shs[HD];
    int t = threadIdx.x;
    if (t < HD) bn_pre(SQin, gam, bet, 1.f / NN, t, scs, shs);
    __syncthreads();
    int c8 = (t & 15) * 8;
    float4 s0 = *(const float4*)&scs[c8], s1 = *(const float4*)&scs[c8 + 4];
    float4 h0 = *(const float4*)&shs[c8], h1 = *(const float4*)&shs[c8 + 4];
#pragma unroll
    for (int ch = 0; ch < 8; ch++) {
        int row = blockIdx.x * 128 + ch * 16 + (t >> 4);
        if (row < NN) {
            const float* p = X + (size_t)row * HD + c8;
            float4 v0 = *(const float4*)p;
            float4 v1 = *(const float4*)(p + 4);
            float f0 = fmaxf(fmaf(v0.x, s0.x, h0.x), 0.f), f1 = fmaxf(fmaf(v0.y, s0.y, h0.y), 0.f);
            float f2 = fmaxf(fmaf(v0.z, s0.z, h0.z), 0.f), f3 = fmaxf(fmaf(v0.w, s0.w, h0.w), 0.f);
            float f4 = fmaxf(fmaf(v1.x, s1.x, h1.x), 0.f), f5 = fmaxf(fmaf(v1.y, s1.y, h1.y), 0.f);
            float f6 = fmaxf(fmaf(v1.z, s1.z, h1.z), 0.f), f7 = fmaxf(fmaf(v1.w, s1.w, h1.w), 0.f);
            uint4 o;
            o.x = pack2(f0, f1); o.y = pack2(f2, f3);
            o.z = pack2(f4, f5); o.w = pack2(f6, f7);
            *(uint4*)(Yb + (size_t)row * HD + c8) = o;
        }
    }
}

// ---------------- CSR scans (scan2 folded into scan3) ----------------
__global__ __launch_bounds__(1024) void scan1_kernel(const int* __restrict__ deg,
                                                     int* __restrict__ rowptr,
                                                     int* __restrict__ blockSum) {
    __shared__ int s[1024];
    int b = blockIdx.x, t = threadIdx.x;
    int i = b * 1024 + t;
    int v = (i < NN) ? deg[i] : 0;
    s[t] = v;
    __syncthreads();
    for (int off = 1; off < 1024; off <<= 1) {
        int u = (t >= off) ? s[t - off] : 0;
        __syncthreads();
        s[t] += u;
        __syncthreads();
    }
    if (i < NN) rowptr[i] = s[t] - v;
    if (t == 1023) blockSum[b] = s[1023];
}

__global__ __launch_bounds__(1024) void scan3_kernel(int* __restrict__ rowptr,
                                                     int* __restrict__ cursor,
                                                     const int* __restrict__ blockSum,
                                                     int* __restrict__ bucketCursor,
                                                     int nblocks) {
    __shared__ int sOff, sTot;
    int b = blockIdx.x, t = threadIdx.x;
    if (t < 64) {
        int orig = (t < nblocks) ? blockSum[t] : 0;
        int v = orig;
        for (int off = 1; off < 64; off <<= 1) {
            int u = __shfl_up(v, off, 64);
            if (t >= off) v += u;
        }
        if (t == b) sOff = v - orig;
        if (t == nblocks - 1) sTot = v;
    }
    __syncthreads();
    int i = b * 1024 + t;
    if (i < NN) {
        int r = rowptr[i] + sOff;
        rowptr[i] = r;
        cursor[i] = r;
        if ((i & 127) == 0) bucketCursor[i >> 7] = r;
    }
    if (b == nblocks - 1 && t == 0) rowptr[NN] = sTot;
}

// ---------------- bin ----------------
__global__ __launch_bounds__(256) void bin_kernel(const int* __restrict__ src,
                                                  const int* __restrict__ dst,
                                                  const int* __restrict__ attr,
                                                  int* __restrict__ bucketCursor,
                                                  uint2* __restrict__ ebuf) {
    __shared__ int cnt[512];
    __shared__ int sc[512], sc2[512];
    __shared__ int base[512];
    __shared__ int garr[NB];
    __shared__ int wof[NB];
    __shared__ uint2 stage[EPB];
    int t = threadIdx.x;
    int e0 = blockIdx.x * EPB;
    for (int i = t; i < 512; i += 256) cnt[i] = 0;
    __syncthreads();
    int myb[16]; unsigned myv[16]; int myd[16];
#pragma unroll
    for (int j = 0; j < 16; j++) {
        int e = e0 + t + j * 256;
        if (e < NE) {
            int d = dst[e];
            myd[j] = d;
            myv[j] = (unsigned)src[e] | ((unsigned)attr[e] << 16);
            myb[j] = d >> 7;
            atomicAdd(&cnt[myb[j]], 1);
        } else myb[j] = -1;
    }
    __syncthreads();
    for (int k = t; k < 512; k += 256) sc[k] = cnt[k];
    __syncthreads();
    int* sp = sc; int* dp = sc2;
    for (int off = 1; off < 512; off <<= 1) {
        for (int k = t; k < 512; k += 256) dp[k] = sp[k] + (k >= off ? sp[k - off] : 0);
        __syncthreads();
        int* tmp = sp; sp = dp; dp = tmp;
    }
    for (int k = t; k < 512; k += 256) base[k] = sp[k] - cnt[k];
    int total = sp[511];
    __syncthreads();
    for (int b = t; b < NB; b += 256) {
        wof[b] = 0;
        if (cnt[b] > 0) garr[b] = atomicAdd(&bucketCursor[b], cnt[b]);
    }
    __syncthreads();
#pragma unroll
    for (int j = 0; j < 16; j++) {
        if (myb[j] >= 0) {
            int slot = base[myb[j]] + atomicAdd(&wof[myb[j]], 1);
            stage[slot] = make_uint2(myv[j], (unsigned)myd[j]);
        }
    }
    __syncthreads();
    for (int i = t; i < total; i += 256) {
        uint2 u = stage[i];
        int b = (int)(u.y >> 7);
        ebuf[garr[b] + (i - base[b])] = u;
    }
}

// ---------------- place ----------------
__global__ __launch_bounds__(256) void place_kernel(const uint2* __restrict__ ebuf,
                                                    const int* __restrict__ rowptr,
                                                    int* __restrict__ cursor,
                                                    unsigned* __restrict__ csr) {
    int b = blockIdx.x;
    int n0 = b * 128;
    int n1 = n0 + 128; if (n1 > NN) n1 = NN;
    int es = rowptr[n0], ee = rowptr[n1];
    for (int i = es + threadIdx.x; i < ee; i += 256) {
        uint2 u = ebuf[i];
        int pos = atomicAdd(&cursor[u.y], 1);
        csr[pos] = u.x;
    }
}

// ---------------- GINE conv ----------------
__device__ __forceinline__ void gine_acc(const unsigned short* __restrict__ Yb,
                                         const float* __restrict__ elds,
                                         unsigned p, int cq, float mask, float* a) {
    uint4 q = *(const uint4*)(Yb + (size_t)(p & 0xFFFFu) * HD + 8 * cq);
    const float* ep = elds + (p >> 16) * HD + 8 * cq;
    float4 e0 = *(const float4*)ep;
    float4 e1 = *(const float4*)(ep + 4);
    a[0] += mask * fmaxf(bflo(q.x) + e0.x, 0.f);
    a[1] += mask * fmaxf(bfhi(q.x) + e0.y, 0.f);
    a[2] += mask * fmaxf(bflo(q.y) + e0.z, 0.f);
    a[3] += mask * fmaxf(bfhi(q.y) + e0.w, 0.f);
    a[4] += mask * fmaxf(bflo(q.z) + e1.x, 0.f);
    a[5] += mask * fmaxf(bfhi(q.z) + e1.y, 0.f);
    a[6] += mask * fmaxf(bflo(q.w) + e1.z, 0.f);
    a[7] += mask * fmaxf(bfhi(q.w) + e1.w, 0.f);
}

__global__ __launch_bounds__(256) void conv_kernel(const unsigned short* __restrict__ Yb,
                                                   const int* __restrict__ rowptr,
                                                   const unsigned* __restrict__ csr,
                                                   const float* __restrict__ edge_emb,
                                                   const float* __restrict__ eps, int layer,
                                                   unsigned short* __restrict__ Ah,
                                                   unsigned short* __restrict__ Al) {
    __shared__ float elds[8 * HD];
    int t = threadIdx.x;
    ((float4*)elds)[t] = ((const float4*)edge_emb)[t];
    __syncthreads();
    int wave = t >> 6, lane = t & 63;
    int node = blockIdx.x * 4 + wave;
    if (node >= NN) return;
    int sub = lane >> 4, cq = lane & 15;
    int lo = rowptr[node], hi = rowptr[node + 1];
    float a[8];
#pragma unroll
    for (int i = 0; i < 8; i++) a[i] = 0.f;
    for (int base = lo; base < hi; base += 64) {
        unsigned pl = 0;
        int cnt = hi - base; if (cnt > 64) cnt = 64;
        if (base + lane < hi) pl = csr[base + lane];
        int j = 0;
        for (; j + 16 <= cnt; j += 16) {
            unsigned pa = __shfl(pl, j + sub, 64);
            unsigned pb = __shfl(pl, j + 4 + sub, 64);
            unsigned pc = __shfl(pl, j + 8 + sub, 64);
            unsigned pd = __shfl(pl, j + 12 + sub, 64);
            gine_acc(Yb, elds, pa, cq, 1.f, a);
            gine_acc(Yb, elds, pb, cq, 1.f, a);
            gine_acc(Yb, elds, pc, cq, 1.f, a);
            gine_acc(Yb, elds, pd, cq, 1.f, a);
        }
        for (; j + 8 <= cnt; j += 8) {
            unsigned pa = __shfl(pl, j + sub, 64);
            unsigned pb = __shfl(pl, j + 4 + sub, 64);
            gine_acc(Yb, elds, pa, cq, 1.f, a);
            gine_acc(Yb, elds, pb, cq, 1.f, a);
        }
        for (; j < cnt; j += 4) {
            int je = j + sub;
            bool val = (je < cnt);
            unsigned p = __shfl(pl, val ? je : j, 64);
            gine_acc(Yb, elds, p, cq, val ? 1.f : 0.f, a);
        }
    }
#pragma unroll
    for (int i = 0; i < 8; i++) {
        a[i] += __shfl_xor(a[i], 16, 64);
        a[i] += __shfl_xor(a[i], 32, 64);
    }
    if (sub == 0) {
        float g = 1.f + eps[layer];
        uint4 q = *(const uint4*)(Yb + (size_t)node * HD + 8 * cq);
        float o0 = fmaf(g, bflo(q.x), a[0]), o1 = fmaf(g, bfhi(q.x), a[1]);
        float o2 = fmaf(g, bflo(q.y), a[2]), o3 = fmaf(g, bfhi(q.y), a[3]);
        float o4 = fmaf(g, bflo(q.z), a[4]), o5 = fmaf(g, bfhi(q.z), a[5]);
        float o6 = fmaf(g, bflo(q.w), a[6]), o7 = fmaf(g, bfhi(q.w), a[7]);
        uint4 H, L;
        split2(o0, o1, H.x, L.x);
        split2(o2, o3, H.y, L.y);
        split2(o4, o5, H.z, L.z);
        split2(o6, o7, H.w, L.w);
        *(uint4*)(Ah + (size_t)node * HD + 8 * cq) = H;
        *(uint4*)(Al + (size_t)node * HD + 8 * cq) = L;
    }
}

// ------- MFMA matmul, pre-split A (T14 prefetch), FULL 128-col W in LDS; 512 thr ---------
__global__ __launch_bounds__(512) void mm_mfma_pre(const unsigned short* __restrict__ Ah,
                                                   const unsigned short* __restrict__ Al,
                                                   const unsigned short* __restrict__ Wh,
                                                   const unsigned short* __restrict__ Wl,
                                                   const float* __restrict__ bias,
                                                   float* __restrict__ out,
                                                   float* __restrict__ SQout) {
    __shared__ unsigned short WhS[128 * WP];
    __shared__ unsigned short WlS[128 * WP];
    int t = threadIdx.x;
    int rowblk = blockIdx.x;
    int w = t >> 6, lane = t & 63;
    int quad = lane >> 4, nl = lane & 15;
    int row0 = rowblk * 128 + w * 16;
    int rA0 = row0 + nl;
    bool ok0 = rA0 < NN;
    // T14: issue A loads BEFORE W staging so HBM/L2 latency hides under staging+barrier
    bf16x8 pah[4], pal[4];
#pragma unroll
    for (int kc = 0; kc < 4; kc++) {
        int k0 = kc * 32 + quad * 8;
        pah[kc] = ok0 ? *(const bf16x8*)(Ah + (size_t)rA0 * HD + k0) : (bf16x8)0;
        pal[kc] = ok0 ? *(const bf16x8*)(Al + (size_t)rA0 * HD + k0) : (bf16x8)0;
    }
#pragma unroll
    for (int i = 0; i < 4; i++) {
        int idx = t + i * 512;
        int col = idx >> 4, kk = (idx & 15) * 8;
        *(uint4*)(WhS + col * WP + kk) = *(const uint4*)(Wh + (size_t)col * HD + kk);
        *(uint4*)(WlS + col * WP + kk) = *(const uint4*)(Wl + (size_t)col * HD + kk);
    }
    __syncthreads();
    f32x4 acc[8];
#pragma unroll
    for (int i = 0; i < 8; i++) acc[i] = (f32x4){0.f, 0.f, 0.f, 0.f};
#pragma unroll
    for (int kc = 0; kc < 4; kc++) {
        int k0 = kc * 32 + quad * 8;
        bf16x8 a0h = pah[kc];
        bf16x8 a0l = pal[kc];
#pragma unroll
        for (int c = 0; c < 8; c++) {
            int wof = (c * 16 + nl) * WP + k0;
            bf16x8 bh = *(const bf16x8*)(WhS + wof);
            bf16x8 bl = *(const bf16x8*)(WlS + wof);
            acc[c] = __builtin_amdgcn_mfma_f32_16x16x32_bf16(a0h, bh, acc[c], 0, 0, 0);
            acc[c] = __builtin_amdgcn_mfma_f32_16x16x32_bf16(a0l, bh, acc[c], 0, 0, 0);
            acc[c] = __builtin_amdgcn_mfma_f32_16x16x32_bf16(a0h, bl, acc[c], 0, 0, 0);
        }
    }
    int rep = (blockIdx.x & (REP - 1)) * 256;
    int baserow = row0 + quad * 4;
    if (rowblk * 128 + 128 <= NN) {
        // full tile: unguarded epilogue (wave-uniform branch)
#pragma unroll
        for (int c = 0; c < 8; c++) {
            int col = c * 16 + nl;
            float bv = bias ? bias[col] : 0.f;
            f32x4 v = acc[c];
            float s = 0.f, qq = 0.f;
#pragma unroll
            for (int r = 0; r < 4; r++) {
                float val = v[r] + bv;
                out[(size_t)(baserow + r) * HD + col] = val;
                s += val;
                qq += val * val;
            }
            s += __shfl_xor(s, 16, 64);  s += __shfl_xor(s, 32, 64);
            qq += __shfl_xor(qq, 16, 64); qq += __shfl_xor(qq, 32, 64);
            if (quad == 0) {
                atomicAdd(&SQout[rep + col], s);
                atomicAdd(&SQout[rep + 128 + col], qq);
            }
        }
    } else {
#pragma unroll
        for (int c = 0; c < 8; c++) {
            int col = c * 16 + nl;
            float bv = bias ? bias[col] : 0.f;
            f32x4 v = acc[c];
            float s = 0.f, qq = 0.f;
#pragma unroll
            for (int r = 0; r < 4; r++) {
                int grow = baserow + r;
                float val = v[r] + bv;
                if (grow < NN) {
                    out[(size_t)grow * HD + col] = val;
                    s += val;
                    qq += val * val;
                }
            }
            s += __shfl_xor(s, 16, 64);  s += __shfl_xor(s, 32, 64);
            qq += __shfl_xor(qq, 16, 64); qq += __shfl_xor(qq, 32, 64);
            if (quad == 0) {
                atomicAdd(&SQout[rep + col], s);
                atomicAdd(&SQout[rep + 128 + col], qq);
            }
        }
    }
}

// ------- MFMA matmul, fp32 A (T14 prefetch) + fused BN-act + split; 512 thr --------------
__global__ __launch_bounds__(512) void mm_mfma_act(const float* __restrict__ A,
                                                   const unsigned short* __restrict__ Wh,
                                                   const unsigned short* __restrict__ Wl,
                                                   const float* __restrict__ bias,
                                                   const float* __restrict__ SQin,
                                                   const float* __restrict__ gam,
                                                   const float* __restrict__ bet,
                                                   float* __restrict__ out,
                                                   float* __restrict__ SQout) {
    __shared__ unsigned short WhS[128 * WP];
    __shared__ unsigned short WlS[128 * WP];
    __shared__ float scs[HD], shs[HD];
    int t = threadIdx.x;
    int rowblk = blockIdx.x;
    int w = t >> 6, lane = t & 63;
    int quad = lane >> 4, nl = lane & 15;
    int row0 = rowblk * 128 + w * 16;
    int rA0 = row0 + nl;
    bool ok0 = rA0 < NN;
    // T14: issue A loads BEFORE bn_pre + W staging
    float4 pv0[4], pv1[4];
#pragma unroll
    for (int kc = 0; kc < 4; kc++) {
        int k0 = kc * 32 + quad * 8;
        pv0[kc] = ok0 ? *(const float4*)(A + (size_t)rA0 * HD + k0) : make_float4(0, 0, 0, 0);
        pv1[kc] = ok0 ? *(const float4*)(A + (size_t)rA0 * HD + k0 + 4) : make_float4(0, 0, 0, 0);
    }
    if (t < HD) bn_pre(SQin, gam, bet, 1.f / NN, t, scs, shs);
#pragma unroll
    for (int i = 0; i < 4; i++) {
        int idx = t + i * 512;
        int col = idx >> 4, kk = (idx & 15) * 8;
        *(uint4*)(WhS + col * WP + kk) = *(const uint4*)(Wh + (size_t)col * HD + kk);
        *(uint4*)(WlS + col * WP + kk) = *(const uint4*)(Wl + (size_t)col * HD + kk);
    }
    __syncthreads();
    f32x4 acc[8];
#pragma unroll
    for (int i = 0; i < 8; i++) acc[i] = (f32x4){0.f, 0.f, 0.f, 0.f};
#pragma unroll
    for (int kc = 0; kc < 4; kc++) {
        int k0 = kc * 32 + quad * 8;
        float4 s0 = *(const float4*)&scs[k0], s1 = *(const float4*)&scs[k0 + 4];
        float4 t0 = *(const float4*)&shs[k0], t1 = *(const float4*)&shs[k0 + 4];
        bf16x8 a0h, a0l;
        {
            float4 v0 = pv0[kc];
            float4 v1 = pv1[kc];
            float f0 = fmaxf(fmaf(v0.x, s0.x, t0.x), 0.f), f1 = fmaxf(fmaf(v0.y, s0.y, t0.y), 0.f);
            float f2 = fmaxf(fmaf(v0.z, s0.z, t0.z), 0.f), f3 = fmaxf(fmaf(v0.w, s0.w, t0.w), 0.f);
            float f4 = fmaxf(fmaf(v1.x, s1.x, t1.x), 0.f), f5 = fmaxf(fmaf(v1.y, s1.y, t1.y), 0.f);
            float f6 = fmaxf(fmaf(v1.z, s1.z, t1.z), 0.f), f7 = fmaxf(fmaf(v1.w, s1.w, t1.w), 0.f);
            if (!ok0) { f0 = f1 = f2 = f3 = f4 = f5 = f6 = f7 = 0.f; }
            unsigned h0, h1, h2, h3, l0, l1, l2, l3;
            split2(f0, f1, h0, l0); split2(f2, f3, h1, l1);
            split2(f4, f5, h2, l2); split2(f6, f7, h3, l3);
            a0h = __builtin_bit_cast(bf16x8, make_uint4(h0, h1, h2, h3));
            a0l = __builtin_bit_cast(bf16x8, make_uint4(l0, l1, l2, l3));
        }
#pragma unroll
        for (int c = 0; c < 8; c++) {
            int wof = (c * 16 + nl) * WP + k0;
            bf16x8 bh = *(const bf16x8*)(WhS + wof);
            bf16x8 bl = *(const bf16x8*)(WlS + wof);
            acc[c] = __builtin_amdgcn_mfma_f32_16x16x32_bf16(a0h, bh, acc[c], 0, 0, 0);
            acc[c] = __builtin_amdgcn_mfma_f32_16x16x32_bf16(a0l, bh, acc[c], 0, 0, 0);
            acc[c] = __builtin_amdgcn_mfma_f32_16x16x32_bf16(a0h, bl, acc[c], 0, 0, 0);
        }
    }
    int rep = (blockIdx.x & (REP - 1)) * 256;
    int baserow = row0 + quad * 4;
    if (rowblk * 128 + 128 <= NN) {
#pragma unroll
        for (int c = 0; c < 8; c++) {
            int col = c * 16 + nl;
            float bv = bias ? bias[col] : 0.f;
            f32x4 v = acc[c];
            float s = 0.f, qq = 0.f;
#pragma unroll
            for (int r = 0; r < 4; r++) {
                float val = v[r] + bv;
                out[(size_t)(baserow + r) * HD + col] = val;
                s += val;
                qq += val * val;
            }
            s += __shfl_xor(s, 16, 64);  s += __shfl_xor(s, 32, 64);
            qq += __shfl_xor(qq, 16, 64); qq += __shfl_xor(qq, 32, 64);
            if (quad == 0) {
                atomicAdd(&SQout[rep + col], s);
                atomicAdd(&SQout[rep + 128 + col], qq);
            }
        }
    } else {
#pragma unroll
        for (int c = 0; c < 8; c++) {
            int col = c * 16 + nl;
            float bv = bias ? bias[col] : 0.f;
            f32x4 v = acc[c];
            float s = 0.f, qq = 0.f;
#pragma unroll
            for (int r = 0; r < 4; r++) {
                int grow = baserow + r;
                float val = v[r] + bv;
                if (grow < NN) {
                    out[(size_t)grow * HD + col] = val;
                    s += val;
                    qq += val * val;
                }
            }
            s += __shfl_xor(s, 16, 64);  s += __shfl_xor(s, 32, 64);
            qq += __shfl_xor(qq, 16, 64); qq += __shfl_xor(qq, 32, 64);
            if (quad == 0) {
                atomicAdd(&SQout[rep + col], s);
                atomicAdd(&SQout[rep + 128 + col], qq);
            }
        }
    }
}

// ---------------- readout ----------------
__global__ __launch_bounds__(256) void readout_kernel(const float* __restrict__ x,
                                                      const int* __restrict__ batch,
                                                      const float* __restrict__ SQin,
                                                      const float* __restrict__ gam,
                                                      const float* __restrict__ bet,
                                                      float* __restrict__ gout) {
    __shared__ int bat[256];
    __shared__ float scs[HD], shs[HD];
    int t = threadIdx.x;
    int rq = t >> 5, cq = t & 31;
    int r0 = blockIdx.x * 256;
    int i = r0 + t;
    bat[t] = (i < NN) ? batch[i] : -1;
    if (t < HD) bn_pre(SQin, gam, bet, 1.f / NN, t, scs, shs);
    __syncthreads();
    float4 s4 = *(const float4*)&scs[4 * cq];
    float4 h4 = *(const float4*)&shs[4 * cq];
    float4 acc = make_float4(0.f, 0.f, 0.f, 0.f);
    int gcur = -1;
    for (int j = rq; j < 256; j += 8) {
        int r = r0 + j;
        if (r >= NN) break;
        int g = bat[j];
        if (g != gcur) {
            if (gcur >= 0) {
                atomicAdd(&gout[(size_t)gcur * HD + 4 * cq + 0], acc.x);
                atomicAdd(&gout[(size_t)gcur * HD + 4 * cq + 1], acc.y);
                atomicAdd(&gout[(size_t)gcur * HD + 4 * cq + 2], acc.z);
                atomicAdd(&gout[(size_t)gcur * HD + 4 * cq + 3], acc.w);
            }
            acc = make_float4(0.f, 0.f, 0.f, 0.f);
            gcur = g;
        }
        float4 v = *(const float4*)(x + (size_t)r * HD + 4 * cq);
        acc.x += fmaxf(fmaf(v.x, s4.x, h4.x), 0.f);
        acc.y += fmaxf(fmaf(v.y, s4.y, h4.y), 0.f);
        acc.z += fmaxf(fmaf(v.z, s4.z, h4.z), 0.f);
        acc.w += fmaxf(fmaf(v.w, s4.w, h4.w), 0.f);
    }
    if (gcur >= 0) {
        atomicAdd(&gout[(size_t)gcur * HD + 4 * cq + 0], acc.x);
        atomicAdd(&gout[(size_t)gcur * HD + 4 * cq + 1], acc.y);
        atomicAdd(&gout[(size_t)gcur * HD + 4 * cq + 2], acc.z);
        atomicAdd(&gout[(size_t)gcur * HD + 4 * cq + 3], acc.w);
    }
}

// --------- fused head v4: 1024 thr; pre-split W + T14 prefetch (issue-early/write-late) --
__global__ __launch_bounds__(1024) void head_fused(const float* __restrict__ Gp,
                                                   const unsigned short* __restrict__ Whd,
                                                   const unsigned short* __restrict__ Wld,
                                                   const float* __restrict__ g0,
                                                   const float* __restrict__ b0,
                                                   const float* __restrict__ g1,
                                                   const float* __restrict__ b1,
                                                   const float* __restrict__ g2,
                                                   const float* __restrict__ b2,
                                                   const float* __restrict__ g3,
                                                   const float* __restrict__ b3,
                                                   const float* __restrict__ finW,
                                                   float* __restrict__ out) {
    const int AP = 132;
    __shared__ float A_lds[128 * AP];
    __shared__ unsigned short WhS[128 * WP];
    __shared__ unsigned short WlS[128 * WP];
    __shared__ float colS[HD], colQ[HD], scs[HD], shs[HD];
    int t = threadIdx.x;
    if (t < HD) { colS[t] = 0.f; colQ[t] = 0.f; scs[t] = 1.f; shs[t] = 0.f; }
#pragma unroll
    for (int i = 0; i < 4; i++) {
        int idx = t + i * 1024;
        int r = idx >> 5, cq = (idx & 31) * 4;
        *(float4*)&A_lds[r * AP + cq] = *(const float4*)(Gp + (size_t)r * HD + cq);
    }
    int sc_ = t >> 4;            // staging col, iter0 (0..63); iter1 is +64
    int sk_ = (t & 15) * 8;      // staging k-offset
    const float* gs[4] = {g0, g1, g2, g3};  // indexed only with unroll-constant s
    const float* bs[4] = {b0, b1, b2, b3};
    // prefetch stage 0 W into registers
    uint4 ph0 = *(const uint4*)(Whd + (size_t)sc_ * HD + sk_);
    uint4 ph1 = *(const uint4*)(Whd + (size_t)(sc_ + 64) * HD + sk_);
    uint4 pl0 = *(const uint4*)(Wld + (size_t)sc_ * HD + sk_);
    uint4 pl1 = *(const uint4*)(Wld + (size_t)(sc_ + 64) * HD + sk_);
    int w = t >> 6, lane = t & 63;
    int quad = lane >> 4, nl = lane & 15;
    int row0 = (w >> 2) * 32, col0 = (w & 3) * 32;
#pragma unroll
    for (int s = 0; s < 4; s++) {
        // write staged W (registers -> LDS)
        *(uint4*)(WhS + sc_ * WP + sk_) = ph0;
        *(uint4*)(WhS + (sc_ + 64) * WP + sk_) = ph1;
        *(uint4*)(WlS + sc_ * WP + sk_) = pl0;
        *(uint4*)(WlS + (sc_ + 64) * WP + sk_) = pl1;
        __syncthreads();  // W, scs/shs, A ready
        // issue next stage's W loads early: latency hides under MFMA phase
        if (s < 3) {
            const unsigned short* nh = Whd + (size_t)(s + 1) * 16384;
            const unsigned short* nl2 = Wld + (size_t)(s + 1) * 16384;
            ph0 = *(const uint4*)(nh + (size_t)sc_ * HD + sk_);
            ph1 = *(const uint4*)(nh + (size_t)(sc_ + 64) * HD + sk_);
            pl0 = *(const uint4*)(nl2 + (size_t)sc_ * HD + sk_);
            pl1 = *(const uint4*)(nl2 + (size_t)(sc_ + 64) * HD + sk_);
        }
        f32x4 acc[4];
#pragma unroll
        for (int i = 0; i < 4; i++) acc[i] = (f32x4){0.f, 0.f, 0.f, 0.f};
#pragma unroll
        for (int kc = 0; kc < 4; kc++) {
            int k0 = kc * 32 + quad * 8;
            float4 s0 = *(const float4*)&scs[k0], s1 = *(const float4*)&scs[k0 + 4];
            float4 t0 = *(const float4*)&shs[k0], t1 = *(const float4*)&shs[k0 + 4];
            bf16x8 a0h, a0l, a1h, a1l;
            {
                const float* ap = &A_lds[(row0 + nl) * AP + k0];
                float4 v0 = *(const float4*)ap;
                float4 v1 = *(const float4*)(ap + 4);
                float f0 = fmaxf(fmaf(v0.x, s0.x, t0.x), 0.f), f1 = fmaxf(fmaf(v0.y, s0.y, t0.y), 0.f);
                float f2 = fmaxf(fmaf(v0.z, s0.z, t0.z), 0.f), f3 = fmaxf(fmaf(v0.w, s0.w, t0.w), 0.f);
                float f4 = fmaxf(fmaf(v1.x, s1.x, t1.x), 0.f), f5 = fmaxf(fmaf(v1.y, s1.y, t1.y), 0.f);
                float f6 = fmaxf(fmaf(v1.z, s1.z, t1.z), 0.f), f7 = fmaxf(fmaf(v1.w, s1.w, t1.w), 0.f);
                unsigned h0, h1, h2, h3, l0, l1, l2, l3;
                split2(f0, f1, h0, l0); split2(f2, f3, h1, l1);
                split2(f4, f5, h2, l2); split2(f6, f7, h3, l3);
                a0h = __builtin_bit_cast(bf16x8, make_uint4(h0, h1, h2, h3));
                a0l = __builtin_bit_cast(bf16x8, make_uint4(l0, l1, l2, l3));
            }
            {
                const float* ap = &A_lds[(row0 + 16 + nl) * AP + k0];
                float4 v0 = *(const float4*)ap;
                float4 v1 = *(const float4*)(ap + 4);
                float f0 = fmaxf(fmaf(v0.x, s0.x, t0.x), 0.f), f1 = fmaxf(fmaf(v0.y, s0.y, t0.y), 0.f);
                float f2 = fmaxf(fmaf(v0.z, s0.z, t0.z), 0.f), f3 = fmaxf(fmaf(v0.w, s0.w, t0.w), 0.f);
                float f4 = fmaxf(fmaf(v1.x, s1.x, t1.x), 0.f), f5 = fmaxf(fmaf(v1.y, s1.y, t1.y), 0.f);
                float f6 = fmaxf(fmaf(v1.z, s1.z, t1.z), 0.f), f7 = fmaxf(fmaf(v1.w, s1.w, t1.w), 0.f);
                unsigned h0, h1, h2, h3, l0, l1, l2, l3;
                split2(f0, f1, h0, l0); split2(f2, f3, h1, l1);
                split2(f4, f5, h2, l2); split2(f6, f7, h3, l3);
                a1h = __builtin_bit_cast(bf16x8, make_uint4(h0, h1, h2, h3));
                a1l = __builtin_bit_cast(bf16x8, make_uint4(l0, l1, l2, l3));
            }
#pragma unroll
            for (int cc = 0; cc < 2; cc++) {
                int wof = (col0 + cc * 16 + nl) * WP + k0;
                bf16x8 bh = *(const bf16x8*)(WhS + wof);
                bf16x8 bl = *(const bf16x8*)(WlS + wof);
                acc[cc] = __builtin_amdgcn_mfma_f32_16x16x32_bf16(a0h, bh, acc[cc], 0, 0, 0);
                acc[cc] = __builtin_amdgcn_mfma_f32_16x16x32_bf16(a0l, bh, acc[cc], 0, 0, 0);
                acc[cc] = __builtin_amdgcn_mfma_f32_16x16x32_bf16(a0h, bl, acc[cc], 0, 0, 0);
                acc[2 + cc] = __builtin_amdgcn_mfma_f32_16x16x32_bf16(a1h, bh, acc[2 + cc], 0, 0, 0);
                acc[2 + cc] = __builtin_amdgcn_mfma_f32_16x16x32_bf16(a1l, bh, acc[2 + cc], 0, 0, 0);
                acc[2 + cc] = __builtin_amdgcn_mfma_f32_16x16x32_bf16(a1h, bl, acc[2 + cc], 0, 0, 0);
            }
        }
        __syncthreads();  // all A_lds + WhS reads done before overwrite
#pragma unroll
        for (int h = 0; h < 2; h++) {
            int baserow = row0 + h * 16 + quad * 4;
#pragma unroll
            for (int cc = 0; cc < 2; cc++) {
                int col = col0 + cc * 16 + nl;
                f32x4 v = acc[h * 2 + cc];
                float ss = 0.f, qq = 0.f;
#pragma unroll
                for (int r = 0; r < 4; r++) {
                    float val = v[r];
                    A_lds[(baserow + r) * AP + col] = val;
                    ss += val;
                    qq += val * val;
                }
                ss += __shfl_xor(ss, 16, 64);  ss += __shfl_xor(ss, 32, 64);
                qq += __shfl_xor(qq, 16, 64);  qq += __shfl_xor(qq, 32, 64);
                if (quad == 0) {
                    atomicAdd(&colS[col], ss);
                    atomicAdd(&colQ[col], qq);
                }
            }
        }
        __syncthreads();
        if (t < HD) {
            float m = colS[t] * (1.f / NG);
            float var = fmaxf(fmaf(colQ[t], 1.f / NG, -m * m), 0.f);
            float inv = rsqrtf(var + BN_EPS);
            float sc = gs[s][t] * inv;
            scs[t] = sc;
            shs[t] = fmaf(-m, sc, bs[s][t]);
            colS[t] = 0.f;
            colQ[t] = 0.f;
        }
        __syncthreads();
    }
    int r = t >> 3, g = t & 7;
    float ssum = 0.f;
#pragma unroll
    for (int j = 0; j < 16; j++) {
        int c = g * 16 + j;
        float v = fmaxf(fmaf(A_lds[r * AP + c], scs[c], shs[c]), 0.f);
        ssum += v * finW[c];
    }
    ssum += __shfl_xor(ssum, 1, 64);
    ssum += __shfl_xor(ssum, 2, 64);
    ssum += __shfl_xor(ssum, 4, 64);
    if (g == 0) out[r] = ssum;
}

extern "C" void kernel_launch(void* const* d_in, const int* in_sizes, int n_in,
                              void* d_out, int out_size, void* d_ws, size_t ws_size,
                              hipStream_t stream) {
    const int* x_ids = (const int*)d_in[0];
    const int* edge_index = (const int*)d_in[1];
    const int* batch = (const int*)d_in[2];
    const int* edge_attr = (const int*)d_in[3];
    const float* node_emb = (const float*)d_in[4];
    const float* edge_emb = (const float*)d_in[5];
    const float* eps = (const float*)d_in[6];
    const float* init_W1 = (const float*)d_in[7];
    const float* init_b1 = (const float*)d_in[8];
    const float* init_g1 = (const float*)d_in[9];
    const float* init_be1 = (const float*)d_in[10];
    const float* init_W2 = (const float*)d_in[11];
    const float* init_b2 = (const float*)d_in[12];
    const float* init_g2 = (const float*)d_in[13];
    const float* init_be2 = (const float*)d_in[14];
    const float* mp_W1 = (const float*)d_in[15];
    const float* mp_g1 = (const float*)d_in[16];
    const float* mp_be1 = (const float*)d_in[17];
    const float* mp_W2 = (const float*)d_in[18];
    const float* mp_g2 = (const float*)d_in[19];
    const float* mp_be2 = (const float*)d_in[20];
    const float* l1_W1 = (const float*)d_in[21];
    const float* l1_g1 = (const float*)d_in[22];
    const float* l1_b1 = (const float*)d_in[23];
    const float* l1_W2 = (const float*)d_in[24];
    const float* l1_g2 = (const float*)d_in[25];
    const float* l1_b2 = (const float*)d_in[26];
    const float* l2_W1 = (const float*)d_in[27];
    const float* l2_g1 = (const float*)d_in[28];
    const float* l2_b1 = (const float*)d_in[29];
    const float* l2_W2 = (const float*)d_in[30];
    const float* l2_g2 = (const float*)d_in[31];
    const float* l2_b2 = (const float*)d_in[32];
    const float* fin_W = (const float*)d_in[33];

    const int* e_src = edge_index;
    const int* e_dst = edge_index + NE;

    // workspace layout — SQ, Gp, deg contiguous -> ONE memset
    const size_t STG = (size_t)REP * 256;
    float* ws = (float*)d_ws;
    float* X = ws;
    float* Bbuf = X + (size_t)NN * HD;
    unsigned short* Yb = (unsigned short*)Bbuf;      // ALIAS (lifetime disjoint)
    unsigned short* Ah = (unsigned short*)(Bbuf + (size_t)NN * HD);
    unsigned short* Al = Ah + (size_t)NN * HD;
    float* SQ = (float*)(Al + (size_t)NN * HD);      // 14 stages } zeroed
    float* Gp = SQ + 14 * STG;                       //           } as one
    int* deg = (int*)(Gp + NG * HD);                 // pad 50048 } region
    float* Hp = (float*)(deg + 50048);
    float* Hp2 = Hp + NG * HD;
    int* rowptr = (int*)(Hp2 + NG * HD);
    int* cursor = rowptr + 50048;
    int* blockSum = cursor + 50048;
    int* blockOff = blockSum + 64;
    int* bucketCursor = blockOff + 64;
    unsigned* csr = (unsigned*)(bucketCursor + NB);
    unsigned short* Wh = (unsigned short*)(csr + NE);   // 14 segs x 16384
    unsigned short* Wl = Wh + 229376;
    uint2* ebuf = (uint2*)(Wl + 229376);
    (void)Hp; (void)Hp2; (void)blockOff;

    const size_t zero_bytes = (14 * STG + NG * HD) * sizeof(float) + 50048 * sizeof(int);
    hipMemsetAsync(SQ, 0, zero_bytes, stream);

    const int SCAN_BLOCKS = (NN + 1023) / 1024;  // 49
    setup_kernel<<<7146, 256, 0, stream>>>(x_ids, node_emb, Yb, init_W1, init_W2, mp_W1,
                                           mp_W2, l1_W1, l1_W2, l2_W1, l2_W2,
                                           Wh, Wl, e_dst, deg);
    scan1_kernel<<<SCAN_BLOCKS, 1024, 0, stream>>>(deg, rowptr, blockSum);
    scan3_kernel<<<SCAN_BLOCKS, 1024, 0, stream>>>(rowptr, cursor, blockSum, bucketCursor,
                                                   SCAN_BLOCKS);
    bin_kernel<<<(NE + EPB - 1) / EPB, 256, 0, stream>>>(e_src, e_dst, edge_attr,
                                                         bucketCursor, ebuf);
    place_kernel<<<(NN + 127) / 128, 256, 0, stream>>>(ebuf, rowptr, cursor, csr);

    const int mfma_grid = (NN + 127) / 128;  // 391 (full 128-col blocks)
    const int ybn_grid = (NN + 127) / 128;   // 391 (128 rows/block)
    for (int i = 0; i <= NL; i++) {
        const unsigned short* Wh1 = Wh + (size_t)(i == 0 ? 0 : 2 + (i - 1)) * 16384;
        const unsigned short* Wl1 = Wl + (size_t)(i == 0 ? 0 : 2 + (i - 1)) * 16384;
        const unsigned short* Wh2 = Wh + (size_t)(i == 0 ? 1 : 6 + (i - 1)) * 16384;
        const unsigned short* Wl2 = Wl + (size_t)(i == 0 ? 1 : 6 + (i - 1)) * 16384;
        const float* b1 = (i == 0) ? init_b1 : nullptr;
        const float* b2 = (i == 0) ? init_b2 : nullptr;
        const float* g1 = (i == 0) ? init_g1 : mp_g1 + (size_t)(i - 1) * HD;
        const float* be1 = (i == 0) ? init_be1 : mp_be1 + (size_t)(i - 1) * HD;
        const float* gp = (i == 1) ? init_g2 : mp_g2 + (size_t)(i - 2) * HD;
        const float* bp = (i == 1) ? init_be2 : mp_be2 + (size_t)(i - 2) * HD;
        float* Sprev = SQ + (size_t)(2 * i - 1) * STG;
        float* S1 = SQ + (size_t)(2 * i) * STG;
        float* S2 = SQ + (size_t)(2 * i + 1) * STG;

        if (i > 0) ybn_kernel<<<ybn_grid, 256, 0, stream>>>(X, Sprev, gp, bp, Yb);
        conv_kernel<<<(NN + 3) / 4, 256, 0, stream>>>(Yb, rowptr, csr, edge_emb, eps, i, Ah, Al);
        mm_mfma_pre<<<mfma_grid, 512, 0, stream>>>(Ah, Al, Wh1, Wl1, b1, Bbuf, S1);
        mm_mfma_act<<<mfma_grid, 512, 0, stream>>>(Bbuf, Wh2, Wl2, b2, S1, g1, be1, X, S2);
    }

    float* S9 = SQ + 9 * STG;
    readout_kernel<<<(NN + 255) / 256, 256, 0, stream>>>(
        X, batch, S9, mp_g2 + 3 * HD, mp_be2 + 3 * HD, Gp);

    head_fused<<<1, 1024, 0, stream>>>(Gp, Wh + (size_t)10 * 16384, Wl + (size_t)10 * 16384,
                                       l1_g1, l1_b1, l1_g2, l1_b2,
                                       l2_g1, l2_b1, l2_g2, l2_b2,
                                       fin_W, (float*)d_out);
}